// Round 6
// baseline (7443.534 us; speedup 1.0000x reference)
//
#include <hip/hip_runtime.h>
#include <hip/hip_bf16.h>

// Problem constants (from reference)
#define N_NODES  100000
#define N_EDGES  400000
#define N_GRAPHS 4000
#define IN_DIM   128
#define HID      512
#define N_DESC   200
#define N_CLASSES 2
#define MLP1_OUT 500
#define MLP2_OUT 100
#define XIN_DIM  (HID + N_DESC)   // 712

typedef __hip_bfloat16  bf16;
typedef __hip_bfloat162 bf16x2;

// ---------------------------------------------------------------------------
// Dtype-generic load helpers (FT = float or bf16), all produce fp32.
// ---------------------------------------------------------------------------
__device__ __forceinline__ float ldf(const float* p, size_t i) { return p[i]; }
__device__ __forceinline__ float ldf(const bf16* p, size_t i)  { return __bfloat162float(p[i]); }

__device__ __forceinline__ float2 ld2(const float* p, int i) { return ((const float2*)p)[i]; }
__device__ __forceinline__ float2 ld2(const bf16* p, int i)  {
    return __bfloat1622float2(((const bf16x2*)p)[i]);
}

__device__ __forceinline__ void store_out(float* p, float v) { *p = v; }
__device__ __forceinline__ void store_out(bf16* p, float v)  { *p = __float2bfloat16(v); }

// ---------------------------------------------------------------------------
// Runtime dtype detection (flag: 0=fp32, 1=bf16). Decode each sampled word's
// LOW 16 bits as bf16: bf16 data -> sane N(0,1) values; fp32 data -> random
// mantissa bits, ~21% sane. Threshold 60%.
// ---------------------------------------------------------------------------
__global__ __launch_bounds__(256)
void detect_dtype_kernel(const unsigned* __restrict__ words, unsigned nw,
                         int* __restrict__ flag)
{
    __shared__ int s_cnt;
    if (threadIdx.x == 0) s_cnt = 0;
    __syncthreads();
    const int SAMPLES = 2048;
    int sane = 0;
    for (int i = threadIdx.x; i < SAMPLES; i += 256) {
        size_t idx = (size_t)(((unsigned long long)i * 2654435761ull) % nw);
        unsigned w = words[idx];
        float f = __uint_as_float((w & 0xFFFFu) << 16);
        float a = fabsf(f);
        if (f == 0.0f || (a > 1e-8f && a < 1e8f)) sane++;
    }
    atomicAdd(&s_cnt, sane);
    __syncthreads();
    if (threadIdx.x == 0) *flag = (s_cnt * 10 > SAMPLES * 6) ? 1 : 0;
}

// ---------------------------------------------------------------------------
// GEMM: C[M,N] = A[M,K](fp32) @ B[K,N](FT) + bias(FT), relu, TOUT output.
// 128x128 block tile, BK=8, 8x8 micro-tile, 256 threads.
// ---------------------------------------------------------------------------
template<int RELU, typename FT, int MODE, typename TOUT>
__global__ __launch_bounds__(256)
void gemm_kernel(const float* __restrict__ A, const FT* __restrict__ B,
                 const FT* __restrict__ bias, TOUT* __restrict__ C,
                 int M, int N, int K, const int* __restrict__ flag)
{
    if (*flag != MODE) return;
    constexpr int BM = 128, BN = 128, BK = 8, TM = 8, TN = 8;
    __shared__ float As[BK][BM];
    __shared__ float Bs[BK][BN];

    const int tid = threadIdx.x;
    const int tr  = tid >> 4;
    const int tc  = tid & 15;
    const int row0 = blockIdx.y * BM;
    const int col0 = blockIdx.x * BN;

    float acc[TM][TN];
#pragma unroll
    for (int i = 0; i < TM; i++)
#pragma unroll
        for (int j = 0; j < TN; j++) acc[i][j] = 0.f;

    for (int k0 = 0; k0 < K; k0 += BK) {
#pragma unroll
        for (int s = 0; s < 4; s++) {
            int l = tid * 4 + s;
            int i = l >> 3, j = l & 7;
            int gr = row0 + i, gc = k0 + j;
            As[j][i] = (gr < M && gc < K) ? A[(size_t)gr * K + gc] : 0.f;
        }
#pragma unroll
        for (int s = 0; s < 4; s++) {
            int l = tid * 4 + s;
            int j = l >> 7, i = l & 127;
            int gr = k0 + j, gc = col0 + i;
            Bs[j][i] = (gr < K && gc < N) ? ldf(B, (size_t)gr * N + gc) : 0.f;
        }
        __syncthreads();
#pragma unroll
        for (int k = 0; k < BK; k++) {
            float a[TM], b[TN];
#pragma unroll
            for (int i = 0; i < TM; i++) a[i] = As[k][tr * TM + i];
#pragma unroll
            for (int j = 0; j < TN; j++) b[j] = Bs[k][tc * TN + j];
#pragma unroll
            for (int i = 0; i < TM; i++)
#pragma unroll
                for (int j = 0; j < TN; j++)
                    acc[i][j] += a[i] * b[j];
        }
        __syncthreads();
    }

#pragma unroll
    for (int i = 0; i < TM; i++) {
        int gr = row0 + tr * TM + i;
        if (gr >= M) continue;
#pragma unroll
        for (int j = 0; j < TN; j++) {
            int gc = col0 + tc * TN + j;
            if (gc >= N) continue;
            float v = acc[i][j] + ldf(bias, gc);
            if (RELU) v = v > 0.f ? v : 0.f;
            store_out(&C[(size_t)gr * N + gc], v);
        }
    }
}

// ---------------------------------------------------------------------------
// GEMM2 + fused mean-pool: t = relu(A[r,:]@W2 + b2); hg[n2g[n0+r],:] += t.
// A = aggc chunk [M,512] fp32. n2g sorted -> group consecutive rows.
// ---------------------------------------------------------------------------
template<typename FT, int MODE>
__global__ __launch_bounds__(256)
void gemm_pool_kernel(const float* __restrict__ A, const FT* __restrict__ B,
                      const FT* __restrict__ bias, const int* __restrict__ n2g,
                      float* __restrict__ hg, int n0, int M,
                      const int* __restrict__ flag)
{
    if (*flag != MODE) return;
    constexpr int BM = 128, BK = 8, TM = 8, TN = 8;
    __shared__ float As[BK][BM];
    __shared__ float Bs[BK][128];

    const int tid = threadIdx.x;
    const int tr  = tid >> 4;
    const int tc  = tid & 15;
    const int row0 = blockIdx.y * BM;
    const int col0 = blockIdx.x * 128;   // grid.x = 4

    float acc[TM][TN];
#pragma unroll
    for (int i = 0; i < TM; i++)
#pragma unroll
        for (int j = 0; j < TN; j++) acc[i][j] = 0.f;

    for (int k0 = 0; k0 < HID; k0 += BK) {
#pragma unroll
        for (int s = 0; s < 4; s++) {
            int l = tid * 4 + s;
            int i = l >> 3, j = l & 7;
            int gr = row0 + i;
            As[j][i] = (gr < M) ? A[(size_t)gr * HID + k0 + j] : 0.f;
        }
#pragma unroll
        for (int s = 0; s < 4; s++) {
            int l = tid * 4 + s;
            int j = l >> 7, i = l & 127;
            Bs[j][i] = ldf(B, (size_t)(k0 + j) * HID + col0 + i);
        }
        __syncthreads();
#pragma unroll
        for (int k = 0; k < BK; k++) {
            float a[TM], b[TN];
#pragma unroll
            for (int i = 0; i < TM; i++) a[i] = As[k][tr * TM + i];
#pragma unroll
            for (int j = 0; j < TN; j++) b[j] = Bs[k][tc * TN + j];
#pragma unroll
            for (int i = 0; i < TM; i++)
#pragma unroll
                for (int j = 0; j < TN; j++)
                    acc[i][j] += a[i] * b[j];
        }
        __syncthreads();
    }

    const int colbase = col0 + tc * TN;
    float pend[TN];
    int gprev = -1;
#pragma unroll
    for (int i = 0; i < TM; i++) {
        int r = row0 + tr * TM + i;
        if (r >= M) break;
        int g = n2g[n0 + r];
        if (g != gprev) {
            if (gprev >= 0) {
#pragma unroll
                for (int j = 0; j < TN; j++)
                    atomicAdd(&hg[(size_t)gprev * HID + colbase + j], pend[j]);
            }
#pragma unroll
            for (int j = 0; j < TN; j++) pend[j] = 0.f;
            gprev = g;
        }
#pragma unroll
        for (int j = 0; j < TN; j++) {
            float v = acc[i][j] + ldf(bias, colbase + j);
            pend[j] += (v > 0.f ? v : 0.f);
        }
    }
    if (gprev >= 0) {
#pragma unroll
        for (int j = 0; j < TN; j++)
            atomicAdd(&hg[(size_t)gprev * HID + colbase + j], pend[j]);
    }
}

// ---------------------------------------------------------------------------
// Layer-1 scatter (full range): agg1[dst[e], 0:128] += feat[src[e], 0:128]
// Wave per edge, grid-stride, fp32 atomics.
// ---------------------------------------------------------------------------
template<typename FT, int MODE>
__global__ __launch_bounds__(256)
void scatter_feat_kernel(const FT* __restrict__ feat, const int* __restrict__ src,
                         const int* __restrict__ dst, float* __restrict__ agg1,
                         const int* __restrict__ flag)
{
    if (*flag != MODE) return;
    int wid  = (blockIdx.x * 256 + threadIdx.x) >> 6;
    int lane = threadIdx.x & 63;
    int nw   = (gridDim.x * 256) >> 6;
    for (int e = wid; e < N_EDGES; e += nw) {
        int d = dst[e];                  // wave-uniform
        int s = src[e];
        float2 f = ld2(feat + (size_t)s * IN_DIM, lane);
        float* o = agg1 + (size_t)d * IN_DIM + lane * 2;
        atomicAdd(o + 0, f.x);
        atomicAdd(o + 1, f.y);
    }
}

// ---------------------------------------------------------------------------
// Layer-2 scatter (chunked over dst): aggc[(d-n0), 0:512] += h1[src[e], 0:512]
// Wave per edge; h1 is internal bf16 -> mode-independent.
// ---------------------------------------------------------------------------
__global__ __launch_bounds__(256)
void scatter_h_chunk(const bf16* __restrict__ h1, const int* __restrict__ src,
                     const int* __restrict__ dst, float* __restrict__ aggc,
                     int n0, int n1)
{
    int wid  = (blockIdx.x * 256 + threadIdx.x) >> 6;
    int lane = threadIdx.x & 63;
    int nw   = (gridDim.x * 256) >> 6;
    for (int e = wid; e < N_EDGES; e += nw) {
        int d = dst[e];                  // wave-uniform
        if (d < n0 || d >= n1) continue;
        int s = src[e];
        float4 v4 = ((const float4*)(h1 + (size_t)s * HID))[lane];  // 8 bf16
        const bf16x2* p = (const bf16x2*)&v4;
        float* o = aggc + (size_t)(d - n0) * HID + lane * 8;
#pragma unroll
        for (int i = 0; i < 4; i++) {
            float2 f = __bfloat1622float2(p[i]);
            atomicAdd(o + 2 * i + 0, f.x);
            atomicAdd(o + 2 * i + 1, f.y);
        }
    }
}

// counts[g] = number of nodes in graph g
__global__ __launch_bounds__(256)
void count_nodes_kernel(const int* __restrict__ n2g, float* __restrict__ counts)
{
    int n = blockIdx.x * 256 + threadIdx.x;
    if (n < N_NODES) atomicAdd(&counts[n2g[n]], 1.0f);
}

// xin[g, c] = c < HID ? hg[g,c]/max(counts[g],1) : desc[g, c-HID]
template<typename FT, int MODE>
__global__ __launch_bounds__(256)
void build_xin_kernel(const float* __restrict__ hg, const float* __restrict__ counts,
                      const FT* __restrict__ desc, float* __restrict__ xin,
                      const int* __restrict__ flag)
{
    if (*flag != MODE) return;
    int idx = blockIdx.x * 256 + threadIdx.x;
    if (idx >= N_GRAPHS * XIN_DIM) return;
    int g = idx / XIN_DIM;
    int c = idx - g * XIN_DIM;
    float v;
    if (c < HID) {
        float cnt = counts[g];
        v = hg[(size_t)g * HID + c] / (cnt > 1.0f ? cnt : 1.0f);
    } else {
        v = ldf(desc, (size_t)g * N_DESC + (c - HID));
    }
    xin[idx] = v;
}

// out[g, c] = x2[g,:] @ cw[:,c] + cb[c]; output dtype = FT
template<typename FT, int MODE>
__global__ __launch_bounds__(256)
void final_layer_kernel(const float* __restrict__ x2, const FT* __restrict__ cw,
                        const FT* __restrict__ cb, FT* __restrict__ out,
                        const int* __restrict__ flag)
{
    if (*flag != MODE) return;
    int i = blockIdx.x * 256 + threadIdx.x;
    if (i >= N_GRAPHS * N_CLASSES) return;
    int r = i >> 1, c = i & 1;
    float acc = ldf(cb, c);
    const float* x = x2 + (size_t)r * MLP2_OUT;
#pragma unroll 4
    for (int k = 0; k < MLP2_OUT; k++)
        acc += x[k] * ldf(cw, k * N_CLASSES + c);
    store_out(&out[i], acc);
}

// ---------------------------------------------------------------------------
static inline size_t align_up(size_t x, size_t a) { return (x + a - 1) & ~(a - 1); }
static inline int imin(int a, int b) { return a < b ? a : b; }

extern "C" void kernel_launch(void* const* d_in, const int* in_sizes, int n_in,
                              void* d_out, int out_size, void* d_ws, size_t ws_size,
                              hipStream_t stream)
{
    const void* features    = d_in[0];
    const void* descriptors = d_in[1];
    const int*  src         = (const int*)d_in[2];
    const int*  dst         = (const int*)d_in[3];
    const int*  node2graph  = (const int*)d_in[4];
    const void* W1          = d_in[5];
    const void* b1          = d_in[6];
    const void* W2          = d_in[7];
    const void* b2          = d_in[8];
    const void* lw1         = d_in[9];
    const void* lb1         = d_in[10];
    const void* lw2         = d_in[11];
    const void* lb2         = d_in[12];
    const void* cw          = d_in[13];
    const void* cb          = d_in[14];
    (void)in_sizes; (void)n_in; (void)out_size;

    // ---- Workspace layout (fixed ~162 MB + adaptive aggc; ws known >=239 MB) ----
    // [agg1 f32 51.2MB][h1 bf16 102.4MB][hg 8.19MB][counts][flag][aggc f32 rest]
    // Head buffers xin/x1/x2 overlay agg1 (dead after the h1 GEMM).
    char* ws = (char*)d_ws;
    size_t off = 0;
    float* agg1 = (float*)(ws + off);
    off = align_up(off + (size_t)N_NODES * IN_DIM * sizeof(float), 256);   // 51.2 MB
    bf16* h1 = (bf16*)(ws + off);
    off = align_up(off + (size_t)N_NODES * HID * sizeof(bf16), 256);       // +102.4 MB
    float* hg = (float*)(ws + off);
    off = align_up(off + (size_t)N_GRAPHS * HID * sizeof(float), 256);     // +8.19 MB
    float* counts = (float*)(ws + off);
    off = align_up(off + (size_t)N_GRAPHS * sizeof(float), 256);
    int* dflag = (int*)(ws + off);
    off = align_up(off + 256, 256);
    float* aggc = (float*)(ws + off);

    size_t avail = (ws_size > off + (1u << 20)) ? (ws_size - off - (1u << 20)) : 0;
    long long ncl = (long long)(avail / ((size_t)HID * sizeof(float)));
    if (ncl > N_NODES) ncl = N_NODES;
    if (ncl < 1024)    ncl = 1024;
    const int NC   = (int)ncl;
    const int nch2 = (N_NODES + NC - 1) / NC;

    float* xin = (float*)(ws + 0);                         // 11.39 MB
    float* x1  = (float*)(ws + (size_t)12 * 1024 * 1024);  // 8.0 MB
    float* x2  = (float*)(ws + (size_t)21 * 1024 * 1024);  // 1.6 MB (< 51.2 MB)

    // ---- Detect float-tensor dtype on device (flag: 0=fp32, 1=bf16) ----
    detect_dtype_kernel<<<1, 256, 0, stream>>>(
        (const unsigned*)features, (unsigned)(N_NODES * IN_DIM / 2), dflag);

    // ---- Graph-pool setup ----
    hipMemsetAsync(hg, 0, (size_t)N_GRAPHS * HID * sizeof(float), stream);
    hipMemsetAsync(counts, 0, (size_t)N_GRAPHS * sizeof(float), stream);
    count_nodes_kernel<<<(N_NODES + 255) / 256, 256, 0, stream>>>(node2graph, counts);

    // ---- Layer 1: agg1 = segment_sum(feat[src], dst)  (fp32, full range) ----
    hipMemsetAsync(agg1, 0, (size_t)N_NODES * IN_DIM * sizeof(float), stream);
    scatter_feat_kernel<float, 0><<<2048, 256, 0, stream>>>(
        (const float*)features, src, dst, agg1, dflag);
    scatter_feat_kernel<bf16, 1><<<2048, 256, 0, stream>>>(
        (const bf16*)features, src, dst, agg1, dflag);

    // ---- h1 = relu(agg1 @ W1 + b1), stored bf16 [N_NODES, 512] ----
    {
        dim3 grid(HID / 128, (N_NODES + 127) / 128);
        gemm_kernel<1, float, 0, bf16><<<grid, 256, 0, stream>>>(
            agg1, (const float*)W1, (const float*)b1, h1,
            N_NODES, HID, IN_DIM, dflag);
        gemm_kernel<1, bf16, 1, bf16><<<grid, 256, 0, stream>>>(
            agg1, (const bf16*)W1, (const bf16*)b1, h1,
            N_NODES, HID, IN_DIM, dflag);
    }

    // ---- Layer 2 (chunked over dst): scatter h1, then GEMM + fused pool ----
    for (int c = 0; c < nch2; c++) {
        int n0 = c * NC, n1 = imin(n0 + NC, N_NODES), mc = n1 - n0;
        hipMemsetAsync(aggc, 0, (size_t)mc * HID * sizeof(float), stream);
        scatter_h_chunk<<<2048, 256, 0, stream>>>(h1, src, dst, aggc, n0, n1);
        dim3 grid(HID / 128, (mc + 127) / 128);
        gemm_pool_kernel<float, 0><<<grid, 256, 0, stream>>>(
            aggc, (const float*)W2, (const float*)b2, node2graph, hg, n0, mc, dflag);
        gemm_pool_kernel<bf16, 1><<<grid, 256, 0, stream>>>(
            aggc, (const bf16*)W2, (const bf16*)b2, node2graph, hg, n0, mc, dflag);
    }

    // ---- Head ----
    {
        int nthr = (N_GRAPHS * XIN_DIM + 255) / 256;
        build_xin_kernel<float, 0><<<nthr, 256, 0, stream>>>(
            hg, counts, (const float*)descriptors, xin, dflag);
        build_xin_kernel<bf16, 1><<<nthr, 256, 0, stream>>>(
            hg, counts, (const bf16*)descriptors, xin, dflag);
    }
    {
        dim3 grid((MLP1_OUT + 127) / 128, (N_GRAPHS + 127) / 128);
        gemm_kernel<1, float, 0, float><<<grid, 256, 0, stream>>>(
            xin, (const float*)lw1, (const float*)lb1, x1,
            N_GRAPHS, MLP1_OUT, XIN_DIM, dflag);
        gemm_kernel<1, bf16, 1, float><<<grid, 256, 0, stream>>>(
            xin, (const bf16*)lw1, (const bf16*)lb1, x1,
            N_GRAPHS, MLP1_OUT, XIN_DIM, dflag);
    }
    {
        dim3 grid((MLP2_OUT + 127) / 128, (N_GRAPHS + 127) / 128);
        gemm_kernel<1, float, 0, float><<<grid, 256, 0, stream>>>(
            x1, (const float*)lw2, (const float*)lb2, x2,
            N_GRAPHS, MLP2_OUT, MLP1_OUT, dflag);
        gemm_kernel<1, bf16, 1, float><<<grid, 256, 0, stream>>>(
            x1, (const bf16*)lw2, (const bf16*)lb2, x2,
            N_GRAPHS, MLP2_OUT, MLP1_OUT, dflag);
    }
    {
        int nthr = (N_GRAPHS * N_CLASSES + 255) / 256;
        final_layer_kernel<float, 0><<<nthr, 256, 0, stream>>>(
            x2, (const float*)cw, (const float*)cb, (float*)d_out, dflag);
        final_layer_kernel<bf16, 1><<<nthr, 256, 0, stream>>>(
            x2, (const bf16*)cw, (const bf16*)cb, (bf16*)d_out, dflag);
    }
}

// Round 7
// 1164.901 us; speedup vs baseline: 6.3898x; 6.3898x over previous
//
#include <hip/hip_runtime.h>
#include <hip/hip_bf16.h>

// Problem constants (from reference)
#define N_NODES  100000
#define N_EDGES  400000
#define N_GRAPHS 4000
#define IN_DIM   128
#define HID      512
#define N_DESC   200
#define N_CLASSES 2
#define MLP1_OUT 500
#define MLP2_OUT 100
#define XIN_DIM  (HID + N_DESC)   // 712

#define SCAN_CHUNK 1024
#define NCHK ((N_NODES + SCAN_CHUNK - 1) / SCAN_CHUNK)   // 98
#define POOL_CHUNK 12500                                  // 8 chunks of 12500 rows

typedef __hip_bfloat16  bf16;
typedef __hip_bfloat162 bf16x2;
typedef short s8v  __attribute__((ext_vector_type(8)));   // 8 bf16 (4 VGPRs), per guide
typedef float f32x4 __attribute__((ext_vector_type(4)));

// ---------------------------------------------------------------------------
// Dtype-generic helpers (FT = float or bf16), all produce fp32.
// ---------------------------------------------------------------------------
__device__ __forceinline__ float ldf(const float* p, size_t i) { return p[i]; }
__device__ __forceinline__ float ldf(const bf16* p, size_t i)  { return __bfloat162float(p[i]); }

__device__ __forceinline__ float2 ld2(const float* p, int i) { return ((const float2*)p)[i]; }
__device__ __forceinline__ float2 ld2(const bf16* p, int i)  {
    return __bfloat1622float2(((const bf16x2*)p)[i]);
}

__device__ __forceinline__ void store_out(float* p, float v) { *p = v; }
__device__ __forceinline__ void store_out(bf16* p, float v)  { *p = __float2bfloat16(v); }

__device__ __forceinline__ short f2bs(float x) {
    bf16 h = __float2bfloat16(x);
    return __builtin_bit_cast(short, h);
}

// stage 8 elements -> 16B of packed bf16 (as float4 for LDS store)
__device__ __forceinline__ float4 stage8(const short* p) { return *(const float4*)p; }
__device__ __forceinline__ float4 stage8(const float* p) {
    float4 a = ((const float4*)p)[0];
    float4 b = ((const float4*)p)[1];
    s8v s;
    s[0] = f2bs(a.x); s[1] = f2bs(a.y); s[2] = f2bs(a.z); s[3] = f2bs(a.w);
    s[4] = f2bs(b.x); s[5] = f2bs(b.y); s[6] = f2bs(b.z); s[7] = f2bs(b.w);
    return __builtin_bit_cast(float4, s);
}

// ---------------------------------------------------------------------------
// Runtime dtype detection (flag: 0=fp32, 1=bf16); see round-5 notes.
// ---------------------------------------------------------------------------
__global__ __launch_bounds__(256)
void detect_dtype_kernel(const unsigned* __restrict__ words, unsigned nw,
                         int* __restrict__ flag)
{
    __shared__ int s_cnt;
    if (threadIdx.x == 0) s_cnt = 0;
    __syncthreads();
    const int SAMPLES = 2048;
    int sane = 0;
    for (int i = threadIdx.x; i < SAMPLES; i += 256) {
        size_t idx = (size_t)(((unsigned long long)i * 2654435761ull) % nw);
        unsigned w = words[idx];
        float f = __uint_as_float((w & 0xFFFFu) << 16);
        float a = fabsf(f);
        if (f == 0.0f || (a > 1e-8f && a < 1e8f)) sane++;
    }
    atomicAdd(&s_cnt, sane);
    __syncthreads();
    if (threadIdx.x == 0) *flag = (s_cnt * 10 > SAMPLES * 6) ? 1 : 0;
}

// ---------------------------------------------------------------------------
// Weight prep (dual-mode): Wt[n*K+k] = bf16(W[k*N+n]); bias -> fp32.
// ---------------------------------------------------------------------------
template<typename FT, int MODE>
__global__ __launch_bounds__(256)
void prep_wt_kernel(const FT* __restrict__ W, short* __restrict__ Wt,
                    int K, int N, const int* __restrict__ flag)
{
    if (*flag != MODE) return;
    int idx = blockIdx.x * 256 + threadIdx.x;
    if (idx >= K * N) return;
    int k = idx / N, n = idx - k * N;
    Wt[(size_t)n * K + k] = f2bs(ldf(W, idx));
}

template<typename FT, int MODE>
__global__ __launch_bounds__(256)
void prep_bias_kernel(const FT* __restrict__ b, float* __restrict__ bf, int n,
                      const int* __restrict__ flag)
{
    if (*flag != MODE) return;
    int i = blockIdx.x * 256 + threadIdx.x;
    if (i < n) bf[i] = ldf(b, i);
}

// ---------------------------------------------------------------------------
// CSR build: deg histogram -> two-level exclusive scan -> fill
// ---------------------------------------------------------------------------
__global__ __launch_bounds__(256)
void deg_kernel(const int* __restrict__ dst, int* __restrict__ deg)
{
    int e = blockIdx.x * 256 + threadIdx.x;
    if (e < N_EDGES) atomicAdd(&deg[dst[e]], 1);
}

__global__ __launch_bounds__(256)
void scan_partial_kernel(const int* __restrict__ deg, int* __restrict__ part)
{
    int c = blockIdx.x, t = threadIdx.x;
    int i0 = c * SCAN_CHUNK + t * 4;
    int s = 0;
#pragma unroll
    for (int j = 0; j < 4; j++) {
        int i = i0 + j;
        if (i < N_NODES) s += deg[i];
    }
    __shared__ int red[256];
    red[t] = s;
    __syncthreads();
    for (int off = 128; off > 0; off >>= 1) {
        if (t < off) red[t] += red[t + off];
        __syncthreads();
    }
    if (t == 0) part[c] = red[0];
}

__global__ void scan_parts_kernel(int* __restrict__ part, int* __restrict__ edge_start)
{
    int run = 0;
    for (int c = 0; c < NCHK; c++) { int v = part[c]; part[c] = run; run += v; }
    edge_start[N_NODES] = run;
}

__global__ __launch_bounds__(256)
void scan_final_kernel(const int* __restrict__ deg, const int* __restrict__ part,
                       int* __restrict__ edge_start)
{
    int c = blockIdx.x, t = threadIdx.x;
    int i0 = c * SCAN_CHUNK + t * 4;
    int d[4];
    int tsum = 0;
#pragma unroll
    for (int j = 0; j < 4; j++) {
        int i = i0 + j;
        d[j] = (i < N_NODES) ? deg[i] : 0;
        tsum += d[j];
    }
    __shared__ int s[256];
    s[t] = tsum;
    __syncthreads();
    for (int off = 1; off < 256; off <<= 1) {
        int v = (t >= off) ? s[t - off] : 0;
        __syncthreads();
        s[t] += v;
        __syncthreads();
    }
    int run = part[c] + s[t] - tsum;
#pragma unroll
    for (int j = 0; j < 4; j++) {
        int i = i0 + j;
        if (i < N_NODES) { edge_start[i] = run; run += d[j]; }
    }
}

__global__ __launch_bounds__(256)
void cursor_kernel(const int* __restrict__ edge_start, int* __restrict__ cursor)
{
    int n = blockIdx.x * 256 + threadIdx.x;
    if (n < N_NODES) cursor[n] = edge_start[n];
}

__global__ __launch_bounds__(256)
void fill_kernel(const int* __restrict__ src, const int* __restrict__ dst,
                 int* __restrict__ cursor, int* __restrict__ csr_src)
{
    int e = blockIdx.x * 256 + threadIdx.x;
    if (e >= N_EDGES) return;
    int p = atomicAdd(&cursor[dst[e]], 1);
    csr_src[p] = src[e];
}

// ---------------------------------------------------------------------------
// Layer-1 gather: agg1[n,0:128] = sum_{e: dst=n} feat[src[e],0:128]  (bf16 out)
// One wave per node; lane holds 2 columns.
// ---------------------------------------------------------------------------
template<typename FT, int MODE>
__global__ __launch_bounds__(256)
void gather_feat_kernel(const FT* __restrict__ feat, const int* __restrict__ edge_start,
                        const int* __restrict__ csr_src, bf16* __restrict__ agg1,
                        const int* __restrict__ flag)
{
    if (*flag != MODE) return;
    int n = blockIdx.x * 4 + (threadIdx.x >> 6);
    if (n >= N_NODES) return;
    int lane = threadIdx.x & 63;
    int e0 = edge_start[n], e1 = edge_start[n + 1];
    float2 acc = {0.f, 0.f};
    for (int i = e0; i < e1; i++) {
        int s = csr_src[i];
        float2 f = ld2(feat + (size_t)s * IN_DIM, lane);
        acc.x += f.x; acc.y += f.y;
    }
    bf16x2 p;
    p.x = __float2bfloat16(acc.x);
    p.y = __float2bfloat16(acc.y);
    ((bf16x2*)(agg1 + (size_t)n * IN_DIM))[lane] = p;
}

// ---------------------------------------------------------------------------
// Layer-2 gather (node range [n0,n1)): aggc[n-n0,0:512] = sum h1[src,0:512]
// One wave per node; lane holds 8 columns (16B loads/stores). fp32 out.
// ---------------------------------------------------------------------------
__global__ __launch_bounds__(256)
void gather_h_kernel(const bf16* __restrict__ h1, const int* __restrict__ edge_start,
                     const int* __restrict__ csr_src, float* __restrict__ aggc,
                     int n0, int n1)
{
    int n = n0 + blockIdx.x * 4 + (threadIdx.x >> 6);
    if (n >= n1) return;
    int lane = threadIdx.x & 63;
    int e0 = edge_start[n], e1 = edge_start[n + 1];
    float acc[8];
#pragma unroll
    for (int j = 0; j < 8; j++) acc[j] = 0.f;
    for (int i = e0; i < e1; i++) {
        int s = csr_src[i];
        float4 r = ((const float4*)(h1 + (size_t)s * HID))[lane];
        const bf16x2* p = (const bf16x2*)&r;
#pragma unroll
        for (int q = 0; q < 4; q++) {
            float2 f = __bfloat1622float2(p[q]);
            acc[2 * q] += f.x; acc[2 * q + 1] += f.y;
        }
    }
    float* orow = aggc + (size_t)(n - n0) * HID + lane * 8;
    ((float4*)orow)[0] = make_float4(acc[0], acc[1], acc[2], acc[3]);
    ((float4*)orow)[1] = make_float4(acc[4], acc[5], acc[6], acc[7]);
}

// ---------------------------------------------------------------------------
// MFMA bf16 GEMM: C[M,512] = A[M,K] @ Bt[512,K]^T (+biasf, relu).
// 128x128 block tile, BK=64, 4 waves (2x2 of 64x64), 16x16x32 MFMA.
// POOL=0: store bf16 C. POOL=1: grouped atomicAdd into hg[n2g[n0+row], col].
// ABT: short (bf16 storage) or float (converted while staging).
// Frag layouts per guide §3 (m89/m91-verified):
//   A: [m=lane&15][k=(lane>>4)*8+j]   C/D: col=lane&15, row=(lane>>4)*4+reg
// ---------------------------------------------------------------------------
template<int POOL, typename ABT>
__global__ __launch_bounds__(256)
void mfma_gemm_kernel(const ABT* __restrict__ A, const short* __restrict__ Bt,
                      const float* __restrict__ biasf, bf16* __restrict__ Cout,
                      const int* __restrict__ n2g, float* __restrict__ hg,
                      int n0, int M, int K)
{
    __shared__ short As[128][72];   // 64 + 8 pad (2-way bank aliasing = free)
    __shared__ short Bs[128][72];

    const int tid  = threadIdx.x;
    const int lane = tid & 63;
    const int wave = tid >> 6;
    const int wr = wave >> 1, wc = wave & 1;
    const int m  = lane & 15, q = lane >> 4;
    const int row0 = blockIdx.y * 128;
    const int col0 = blockIdx.x * 128;

    f32x4 acc[4][4];
#pragma unroll
    for (int i = 0; i < 4; i++)
#pragma unroll
        for (int j = 0; j < 4; j++) acc[i][j] = {0.f, 0.f, 0.f, 0.f};

    for (int k0 = 0; k0 < K; k0 += 64) {
        // stage A tile: 128 rows x 64 cols bf16; 1024 16B segments
#pragma unroll
        for (int i = 0; i < 4; i++) {
            int seg = tid + i * 256;
            int r = seg >> 3, o = seg & 7;
            int gr = row0 + r;
            float4 v = make_float4(0.f, 0.f, 0.f, 0.f);
            if (gr < M) v = stage8(A + (size_t)gr * K + k0 + o * 8);
            *(float4*)&As[r][o * 8] = v;
        }
        // stage Bt tile (rows = output cols, always < 512)
#pragma unroll
        for (int i = 0; i < 4; i++) {
            int seg = tid + i * 256;
            int r = seg >> 3, o = seg & 7;
            *(float4*)&Bs[r][o * 8] =
                *(const float4*)(Bt + (size_t)(col0 + r) * K + k0 + o * 8);
        }
        __syncthreads();
#pragma unroll
        for (int kq = 0; kq < 2; kq++) {
            s8v av[4], bv[4];
#pragma unroll
            for (int rt = 0; rt < 4; rt++)
                av[rt] = *(const s8v*)&As[wr * 64 + rt * 16 + m][kq * 32 + q * 8];
#pragma unroll
            for (int ct = 0; ct < 4; ct++)
                bv[ct] = *(const s8v*)&Bs[wc * 64 + ct * 16 + m][kq * 32 + q * 8];
#pragma unroll
            for (int rt = 0; rt < 4; rt++)
#pragma unroll
                for (int ct = 0; ct < 4; ct++)
                    acc[rt][ct] = __builtin_amdgcn_mfma_f32_16x16x32_bf16(
                        av[rt], bv[ct], acc[rt][ct], 0, 0, 0);
        }
        __syncthreads();
    }

    // Epilogue
#pragma unroll
    for (int rt = 0; rt < 4; rt++) {
        int rbase = row0 + wr * 64 + rt * 16 + q * 4;
        if (POOL == 0) {
#pragma unroll
            for (int ct = 0; ct < 4; ct++) {
                int col = col0 + wc * 64 + ct * 16 + m;
                float bv = biasf[col];
#pragma unroll
                for (int reg = 0; reg < 4; reg++) {
                    int row = rbase + reg;
                    if (row < M) {
                        float v = acc[rt][ct][reg] + bv;
                        v = v > 0.f ? v : 0.f;
                        Cout[(size_t)row * HID + col] = __float2bfloat16(v);
                    }
                }
            }
        } else {
            int g4[4];
#pragma unroll
            for (int reg = 0; reg < 4; reg++) {
                int row = rbase + reg;
                g4[reg] = (row < M) ? n2g[n0 + row] : -1;
            }
#pragma unroll
            for (int ct = 0; ct < 4; ct++) {
                int col = col0 + wc * 64 + ct * 16 + m;
                float bv = biasf[col];
                float pend = 0.f;
                int gprev = -1;
#pragma unroll
                for (int reg = 0; reg < 4; reg++) {
                    if (g4[reg] < 0) continue;
                    float v = acc[rt][ct][reg] + bv;
                    v = v > 0.f ? v : 0.f;
                    if (g4[reg] != gprev) {
                        if (gprev >= 0)
                            atomicAdd(&hg[(size_t)gprev * HID + col], pend);
                        gprev = g4[reg];
                        pend = 0.f;
                    }
                    pend += v;
                }
                if (gprev >= 0)
                    atomicAdd(&hg[(size_t)gprev * HID + col], pend);
            }
        }
    }
}

// ---------------------------------------------------------------------------
// Head (small): fp32 SGEMM, dual-mode weights (unchanged from round 6).
// ---------------------------------------------------------------------------
template<int RELU, typename FT, int MODE, typename TOUT>
__global__ __launch_bounds__(256)
void gemm_kernel(const float* __restrict__ A, const FT* __restrict__ B,
                 const FT* __restrict__ bias, TOUT* __restrict__ C,
                 int M, int N, int K, const int* __restrict__ flag)
{
    if (*flag != MODE) return;
    constexpr int BM = 128, BN = 128, BK = 8, TM = 8, TN = 8;
    __shared__ float As[BK][BM + 4];
    __shared__ float Bs[BK][BN + 4];

    const int tid = threadIdx.x;
    const int tr  = tid >> 4;
    const int tc  = tid & 15;
    const int row0 = blockIdx.y * BM;
    const int col0 = blockIdx.x * BN;

    float acc[TM][TN];
#pragma unroll
    for (int i = 0; i < TM; i++)
#pragma unroll
        for (int j = 0; j < TN; j++) acc[i][j] = 0.f;

    for (int k0 = 0; k0 < K; k0 += BK) {
#pragma unroll
        for (int s = 0; s < 4; s++) {
            int l = tid * 4 + s;
            int i = l >> 3, j = l & 7;
            int gr = row0 + i, gc = k0 + j;
            As[j][i] = (gr < M && gc < K) ? A[(size_t)gr * K + gc] : 0.f;
        }
#pragma unroll
        for (int s = 0; s < 4; s++) {
            int l = tid * 4 + s;
            int j = l >> 7, i = l & 127;
            int gr = k0 + j, gc = col0 + i;
            Bs[j][i] = (gr < K && gc < N) ? ldf(B, (size_t)gr * N + gc) : 0.f;
        }
        __syncthreads();
#pragma unroll
        for (int k = 0; k < BK; k++) {
            float a[TM], b[TN];
#pragma unroll
            for (int i = 0; i < TM; i++) a[i] = As[k][tr * TM + i];
#pragma unroll
            for (int j = 0; j < TN; j++) b[j] = Bs[k][tc * TN + j];
#pragma unroll
            for (int i = 0; i < TM; i++)
#pragma unroll
                for (int j = 0; j < TN; j++)
                    acc[i][j] += a[i] * b[j];
        }
        __syncthreads();
    }

#pragma unroll
    for (int i = 0; i < TM; i++) {
        int gr = row0 + tr * TM + i;
        if (gr >= M) continue;
#pragma unroll
        for (int j = 0; j < TN; j++) {
            int gc = col0 + tc * TN + j;
            if (gc >= N) continue;
            float v = acc[i][j] + ldf(bias, gc);
            if (RELU) v = v > 0.f ? v : 0.f;
            store_out(&C[(size_t)gr * N + gc], v);
        }
    }
}

// counts[g] = number of nodes in graph g
__global__ __launch_bounds__(256)
void count_nodes_kernel(const int* __restrict__ n2g, float* __restrict__ counts)
{
    int n = blockIdx.x * 256 + threadIdx.x;
    if (n < N_NODES) atomicAdd(&counts[n2g[n]], 1.0f);
}

// xin[g, c] = c < HID ? hg[g,c]/max(counts[g],1) : desc[g, c-HID]
template<typename FT, int MODE>
__global__ __launch_bounds__(256)
void build_xin_kernel(const float* __restrict__ hg, const float* __restrict__ counts,
                      const FT* __restrict__ desc, float* __restrict__ xin,
                      const int* __restrict__ flag)
{
    if (*flag != MODE) return;
    int idx = blockIdx.x * 256 + threadIdx.x;
    if (idx >= N_GRAPHS * XIN_DIM) return;
    int g = idx / XIN_DIM;
    int c = idx - g * XIN_DIM;
    float v;
    if (c < HID) {
        float cnt = counts[g];
        v = hg[(size_t)g * HID + c] / (cnt > 1.0f ? cnt : 1.0f);
    } else {
        v = ldf(desc, (size_t)g * N_DESC + (c - HID));
    }
    xin[idx] = v;
}

// out[g, c] = x2[g,:] @ cw[:,c] + cb[c]; output dtype = FT
template<typename FT, int MODE>
__global__ __launch_bounds__(256)
void final_layer_kernel(const float* __restrict__ x2, const FT* __restrict__ cw,
                        const FT* __restrict__ cb, FT* __restrict__ out,
                        const int* __restrict__ flag)
{
    if (*flag != MODE) return;
    int i = blockIdx.x * 256 + threadIdx.x;
    if (i >= N_GRAPHS * N_CLASSES) return;
    int r = i >> 1, c = i & 1;
    float acc = ldf(cb, c);
    const float* x = x2 + (size_t)r * MLP2_OUT;
#pragma unroll 4
    for (int k = 0; k < MLP2_OUT; k++)
        acc += x[k] * ldf(cw, k * N_CLASSES + c);
    store_out(&out[i], acc);
}

// ---------------------------------------------------------------------------
static inline size_t align_up(size_t x, size_t a) { return (x + a - 1) & ~(a - 1); }

extern "C" void kernel_launch(void* const* d_in, const int* in_sizes, int n_in,
                              void* d_out, int out_size, void* d_ws, size_t ws_size,
                              hipStream_t stream)
{
    const void* features    = d_in[0];
    const void* descriptors = d_in[1];
    const int*  src         = (const int*)d_in[2];
    const int*  dst         = (const int*)d_in[3];
    const int*  node2graph  = (const int*)d_in[4];
    const void* W1          = d_in[5];
    const void* b1          = d_in[6];
    const void* W2          = d_in[7];
    const void* b2          = d_in[8];
    const void* lw1         = d_in[9];
    const void* lb1         = d_in[10];
    const void* lw2         = d_in[11];
    const void* lb2         = d_in[12];
    const void* cw          = d_in[13];
    const void* cb          = d_in[14];
    (void)in_sizes; (void)n_in; (void)out_size; (void)ws_size;

    // ---- Workspace layout (fixed ~140 MB; proven ws >= ~166 MB) ----
    char* ws = (char*)d_ws;
    size_t off = 0;
    // R0 (25.6 MB): agg1 bf16 [100000,128]  -> later aggc fp32 [12500,512]
    bf16*  agg1 = (bf16*)(ws + off);
    float* aggc = (float*)(ws + off);
    off = align_up(off + 25600000, 256);
    // R1 (102.4 MB): h1 bf16 [100000,512] -> later head buffers
    bf16* h1 = (bf16*)(ws + off);
    float* xin = (float*)(ws + off);                        // 11.39 MB
    float* x1  = (float*)(ws + off + (size_t)12 * 1024 * 1024);
    float* x2  = (float*)(ws + off + (size_t)21 * 1024 * 1024);
    off = align_up(off + (size_t)N_NODES * HID * sizeof(bf16), 256);
    float* hg = (float*)(ws + off);
    off = align_up(off + (size_t)N_GRAPHS * HID * sizeof(float), 256);
    float* counts = (float*)(ws + off);
    off = align_up(off + (size_t)N_GRAPHS * sizeof(float), 256);
    int* dflag = (int*)(ws + off);          off = align_up(off + 256, 256);
    int* edge_start = (int*)(ws + off);     off = align_up(off + (N_NODES + 1) * 4, 256);
    int* cursor = (int*)(ws + off);         off = align_up(off + N_NODES * 4, 256);
    int* csr_src = (int*)(ws + off);        off = align_up(off + N_EDGES * 4, 256);
    int* part = (int*)(ws + off);           off = align_up(off + NCHK * 4, 256);
    short* W1t = (short*)(ws + off);        off = align_up(off + IN_DIM * HID * 2, 256);
    short* W2t = (short*)(ws + off);        off = align_up(off + HID * HID * 2, 256);
    float* b1f = (float*)(ws + off);        off = align_up(off + HID * 4, 256);
    float* b2f = (float*)(ws + off);        off = align_up(off + HID * 4, 256);
    int* deg = (int*)(ws + off);            off = align_up(off + N_NODES * 4, 256);

    // ---- Detect float-tensor dtype (flag: 0=fp32, 1=bf16) ----
    detect_dtype_kernel<<<1, 256, 0, stream>>>(
        (const unsigned*)features, (unsigned)(N_NODES * IN_DIM / 2), dflag);

    // ---- Weight prep (transpose to [N,K] bf16; biases to fp32) ----
    prep_wt_kernel<float, 0><<<(IN_DIM * HID + 255) / 256, 256, 0, stream>>>(
        (const float*)W1, W1t, IN_DIM, HID, dflag);
    prep_wt_kernel<bf16, 1><<<(IN_DIM * HID + 255) / 256, 256, 0, stream>>>(
        (const bf16*)W1, W1t, IN_DIM, HID, dflag);
    prep_wt_kernel<float, 0><<<(HID * HID + 255) / 256, 256, 0, stream>>>(
        (const float*)W2, W2t, HID, HID, dflag);
    prep_wt_kernel<bf16, 1><<<(HID * HID + 255) / 256, 256, 0, stream>>>(
        (const bf16*)W2, W2t, HID, HID, dflag);
    prep_bias_kernel<float, 0><<<2, 256, 0, stream>>>((const float*)b1, b1f, HID, dflag);
    prep_bias_kernel<bf16, 1><<<2, 256, 0, stream>>>((const bf16*)b1, b1f, HID, dflag);
    prep_bias_kernel<float, 0><<<2, 256, 0, stream>>>((const float*)b2, b2f, HID, dflag);
    prep_bias_kernel<bf16, 1><<<2, 256, 0, stream>>>((const bf16*)b2, b2f, HID, dflag);

    // ---- Pool setup ----
    hipMemsetAsync(hg, 0, (size_t)N_GRAPHS * HID * sizeof(float), stream);
    hipMemsetAsync(counts, 0, (size_t)N_GRAPHS * sizeof(float), stream);
    count_nodes_kernel<<<(N_NODES + 255) / 256, 256, 0, stream>>>(node2graph, counts);

    // ---- CSR build (counting sort by dst) ----
    hipMemsetAsync(deg, 0, N_NODES * 4, stream);
    deg_kernel<<<(N_EDGES + 255) / 256, 256, 0, stream>>>(dst, deg);
    scan_partial_kernel<<<NCHK, 256, 0, stream>>>(deg, part);
    scan_parts_kernel<<<1, 1, 0, stream>>>(part, edge_start);
    scan_final_kernel<<<NCHK, 256, 0, stream>>>(deg, part, edge_start);
    cursor_kernel<<<(N_NODES + 255) / 256, 256, 0, stream>>>(edge_start, cursor);
    fill_kernel<<<(N_EDGES + 255) / 256, 256, 0, stream>>>(src, dst, cursor, csr_src);

    // ---- Layer 1: gather -> agg1 (bf16), then MFMA GEMM -> h1 (bf16) ----
    gather_feat_kernel<float, 0><<<N_NODES / 4, 256, 0, stream>>>(
        (const float*)features, edge_start, csr_src, agg1, dflag);
    gather_feat_kernel<bf16, 1><<<N_NODES / 4, 256, 0, stream>>>(
        (const bf16*)features, edge_start, csr_src, agg1, dflag);
    {
        dim3 grid(HID / 128, (N_NODES + 127) / 128);
        mfma_gemm_kernel<0, short><<<grid, 256, 0, stream>>>(
            (const short*)agg1, W1t, b1f, h1, nullptr, nullptr, 0, N_NODES, IN_DIM);
    }

    // ---- Layer 2 (8 chunks of 12500 nodes): gather h1 -> aggc fp32,
    //      MFMA GEMM + fused mean-pool numerator into hg ----
    for (int c = 0; c < N_NODES / POOL_CHUNK; c++) {
        int n0 = c * POOL_CHUNK, n1 = n0 + POOL_CHUNK;
        gather_h_kernel<<<POOL_CHUNK / 4, 256, 0, stream>>>(
            h1, edge_start, csr_src, aggc, n0, n1);
        dim3 grid(HID / 128, (POOL_CHUNK + 127) / 128);
        mfma_gemm_kernel<1, float><<<grid, 256, 0, stream>>>(
            aggc, W2t, b2f, nullptr, node2graph, hg, n0, POOL_CHUNK, HID);
    }

    // ---- Head ----
    {
        int nthr = (N_GRAPHS * XIN_DIM + 255) / 256;
        build_xin_kernel<float, 0><<<nthr, 256, 0, stream>>>(
            hg, counts, (const float*)descriptors, xin, dflag);
        build_xin_kernel<bf16, 1><<<nthr, 256, 0, stream>>>(
            hg, counts, (const bf16*)descriptors, xin, dflag);
    }
    {
        dim3 grid((MLP1_OUT + 127) / 128, (N_GRAPHS + 127) / 128);
        gemm_kernel<1, float, 0, float><<<grid, 256, 0, stream>>>(
            xin, (const float*)lw1, (const float*)lb1, x1,
            N_GRAPHS, MLP1_OUT, XIN_DIM, dflag);
        gemm_kernel<1, bf16, 1, float><<<grid, 256, 0, stream>>>(
            xin, (const bf16*)lw1, (const bf16*)lb1, x1,
            N_GRAPHS, MLP1_OUT, XIN_DIM, dflag);
    }
    {
        dim3 grid((MLP2_OUT + 127) / 128, (N_GRAPHS + 127) / 128);
        gemm_kernel<1, float, 0, float><<<grid, 256, 0, stream>>>(
            x1, (const float*)lw2, (const float*)lb2, x2,
            N_GRAPHS, MLP2_OUT, MLP1_OUT, dflag);
        gemm_kernel<1, bf16, 1, float><<<grid, 256, 0, stream>>>(
            x1, (const bf16*)lw2, (const bf16*)lb2, x2,
            N_GRAPHS, MLP2_OUT, MLP1_OUT, dflag);
    }
    {
        int nthr = (N_GRAPHS * N_CLASSES + 255) / 256;
        final_layer_kernel<float, 0><<<nthr, 256, 0, stream>>>(
            x2, (const float*)cw, (const float*)cb, (float*)d_out, dflag);
        final_layer_kernel<bf16, 1><<<nthr, 256, 0, stream>>>(
            x2, (const bf16*)cw, (const bf16*)cb, (bf16*)d_out, dflag);
    }
}

// Round 8
// 663.887 us; speedup vs baseline: 11.2121x; 1.7547x over previous
//
#include <hip/hip_runtime.h>
#include <hip/hip_bf16.h>

// Problem constants (from reference)
#define N_NODES  100000
#define N_EDGES  400000
#define N_GRAPHS 4000
#define IN_DIM   128
#define HID      512
#define N_DESC   200
#define N_CLASSES 2
#define MLP1_OUT 500
#define MLP2_OUT 100
#define XIN_DIM  (HID + N_DESC)   // 712
#define XIN_PAD  768              // K padded to multiple of 64

#define SCAN_CHUNK 1024
#define NCHK ((N_NODES + SCAN_CHUNK - 1) / SCAN_CHUNK)   // 98

typedef __hip_bfloat16  bf16;
typedef __hip_bfloat162 bf16x2;
typedef short s8v  __attribute__((ext_vector_type(8)));   // 8 bf16 (4 VGPRs)
typedef float f32x4 __attribute__((ext_vector_type(4)));

// ---------------------------------------------------------------------------
// Dtype-generic helpers (FT = float or bf16), all produce fp32.
// ---------------------------------------------------------------------------
__device__ __forceinline__ float ldf(const float* p, size_t i) { return p[i]; }
__device__ __forceinline__ float ldf(const bf16* p, size_t i)  { return __bfloat162float(p[i]); }

__device__ __forceinline__ float2 ld2(const float* p, int i) { return ((const float2*)p)[i]; }
__device__ __forceinline__ float2 ld2(const bf16* p, int i)  {
    return __bfloat1622float2(((const bf16x2*)p)[i]);
}

__device__ __forceinline__ void store_out(float* p, float v) { *p = v; }
__device__ __forceinline__ void store_out(bf16* p, float v)  { *p = __float2bfloat16(v); }

__device__ __forceinline__ short f2bs(float x) {
    bf16 h = __float2bfloat16(x);
    return __builtin_bit_cast(short, h);
}

// stage 8 bf16 elements -> 16B packed (as float4 for LDS store)
__device__ __forceinline__ float4 stage8(const short* p) { return *(const float4*)p; }

// ---------------------------------------------------------------------------
// Runtime dtype detection (flag: 0=fp32, 1=bf16); see round-5 notes.
// ---------------------------------------------------------------------------
__global__ __launch_bounds__(256)
void detect_dtype_kernel(const unsigned* __restrict__ words, unsigned nw,
                         int* __restrict__ flag)
{
    __shared__ int s_cnt;
    if (threadIdx.x == 0) s_cnt = 0;
    __syncthreads();
    const int SAMPLES = 2048;
    int sane = 0;
    for (int i = threadIdx.x; i < SAMPLES; i += 256) {
        size_t idx = (size_t)(((unsigned long long)i * 2654435761ull) % nw);
        unsigned w = words[idx];
        float f = __uint_as_float((w & 0xFFFFu) << 16);
        float a = fabsf(f);
        if (f == 0.0f || (a > 1e-8f && a < 1e8f)) sane++;
    }
    atomicAdd(&s_cnt, sane);
    __syncthreads();
    if (threadIdx.x == 0) *flag = (s_cnt * 10 > SAMPLES * 6) ? 1 : 0;
}

// ---------------------------------------------------------------------------
// Fused weight prep (dual-mode): all weights -> transposed bf16 [N][K]
// (zero-padded), all biases -> fp32 (zero-padded). One launch per mode.
// Segments: W1t 65536 | W2t 262144 | lw1t 393216 | lw2t 65536 |
//           b1f 512 | b2f 512 | lb1f 512 | lb2f 128   (total 788096)
// ---------------------------------------------------------------------------
template<typename FT, int MODE>
__global__ __launch_bounds__(256)
void prep_weights_kernel(const FT* __restrict__ W1, const FT* __restrict__ W2,
                         const FT* __restrict__ lw1, const FT* __restrict__ lw2,
                         const FT* __restrict__ b1, const FT* __restrict__ b2,
                         const FT* __restrict__ lb1, const FT* __restrict__ lb2,
                         short* __restrict__ W1t, short* __restrict__ W2t,
                         short* __restrict__ lw1t, short* __restrict__ lw2t,
                         float* __restrict__ b1f, float* __restrict__ b2f,
                         float* __restrict__ lb1f, float* __restrict__ lb2f,
                         const int* __restrict__ flag)
{
    if (*flag != MODE) return;
    int i = blockIdx.x * 256 + threadIdx.x;
    if (i < 65536) {            // W1t [512][128] <- W1 [128,512]
        int n = i >> 7, k = i & 127;
        W1t[i] = f2bs(ldf(W1, (size_t)k * HID + n));
        return;
    }
    i -= 65536;
    if (i < 262144) {           // W2t [512][512] <- W2 [512,512]
        int n = i >> 9, k = i & 511;
        W2t[i] = f2bs(ldf(W2, (size_t)k * HID + n));
        return;
    }
    i -= 262144;
    if (i < 393216) {           // lw1t [512][768] <- lw1 [712,500], zero-pad
        int n = i / XIN_PAD, k = i - n * XIN_PAD;
        lw1t[i] = (n < MLP1_OUT && k < XIN_DIM)
                      ? f2bs(ldf(lw1, (size_t)k * MLP1_OUT + n)) : (short)0;
        return;
    }
    i -= 393216;
    if (i < 65536) {            // lw2t [128][512] <- lw2 [500,100], zero-pad
        int n = i >> 9, k = i & 511;
        lw2t[i] = (n < MLP2_OUT && k < MLP1_OUT)
                      ? f2bs(ldf(lw2, (size_t)k * MLP2_OUT + n)) : (short)0;
        return;
    }
    i -= 65536;
    if (i < 512) { b1f[i] = ldf(b1, i); return; }
    i -= 512;
    if (i < 512) { b2f[i] = ldf(b2, i); return; }
    i -= 512;
    if (i < 512) { lb1f[i] = (i < MLP1_OUT) ? ldf(lb1, i) : 0.f; return; }
    i -= 512;
    if (i < 128) { lb2f[i] = (i < MLP2_OUT) ? ldf(lb2, i) : 0.f; return; }
}

// ---------------------------------------------------------------------------
// CSR build: deg histogram -> two-level exclusive scan -> fill
// ---------------------------------------------------------------------------
__global__ __launch_bounds__(256)
void deg_kernel(const int* __restrict__ dst, int* __restrict__ deg)
{
    int e = blockIdx.x * 256 + threadIdx.x;
    if (e < N_EDGES) atomicAdd(&deg[dst[e]], 1);
}

__global__ __launch_bounds__(256)
void scan_partial_kernel(const int* __restrict__ deg, int* __restrict__ part)
{
    int c = blockIdx.x, t = threadIdx.x;
    int i0 = c * SCAN_CHUNK + t * 4;
    int s = 0;
#pragma unroll
    for (int j = 0; j < 4; j++) {
        int i = i0 + j;
        if (i < N_NODES) s += deg[i];
    }
    __shared__ int red[256];
    red[t] = s;
    __syncthreads();
    for (int off = 128; off > 0; off >>= 1) {
        if (t < off) red[t] += red[t + off];
        __syncthreads();
    }
    if (t == 0) part[c] = red[0];
}

__global__ void scan_parts_kernel(int* __restrict__ part, int* __restrict__ edge_start)
{
    int run = 0;
    for (int c = 0; c < NCHK; c++) { int v = part[c]; part[c] = run; run += v; }
    edge_start[N_NODES] = run;
}

__global__ __launch_bounds__(256)
void scan_final_kernel(const int* __restrict__ deg, const int* __restrict__ part,
                       int* __restrict__ edge_start)
{
    int c = blockIdx.x, t = threadIdx.x;
    int i0 = c * SCAN_CHUNK + t * 4;
    int d[4];
    int tsum = 0;
#pragma unroll
    for (int j = 0; j < 4; j++) {
        int i = i0 + j;
        d[j] = (i < N_NODES) ? deg[i] : 0;
        tsum += d[j];
    }
    __shared__ int s[256];
    s[t] = tsum;
    __syncthreads();
    for (int off = 1; off < 256; off <<= 1) {
        int v = (t >= off) ? s[t - off] : 0;
        __syncthreads();
        s[t] += v;
        __syncthreads();
    }
    int run = part[c] + s[t] - tsum;
#pragma unroll
    for (int j = 0; j < 4; j++) {
        int i = i0 + j;
        if (i < N_NODES) { edge_start[i] = run; run += d[j]; }
    }
}

__global__ __launch_bounds__(256)
void cursor_kernel(const int* __restrict__ edge_start, int* __restrict__ cursor)
{
    int n = blockIdx.x * 256 + threadIdx.x;
    if (n < N_NODES) cursor[n] = edge_start[n];
}

__global__ __launch_bounds__(256)
void fill_kernel(const int* __restrict__ src, const int* __restrict__ dst,
                 int* __restrict__ cursor, int* __restrict__ csr_src)
{
    int e = blockIdx.x * 256 + threadIdx.x;
    if (e >= N_EDGES) return;
    int p = atomicAdd(&cursor[dst[e]], 1);
    csr_src[p] = src[e];
}

// ---------------------------------------------------------------------------
// Layer-1 gather: agg1[n,0:128] = sum_{e: dst=n} feat[src[e],0:128]  (bf16 out)
// One wave per node; lane holds 2 columns.
// ---------------------------------------------------------------------------
template<typename FT, int MODE>
__global__ __launch_bounds__(256)
void gather_feat_kernel(const FT* __restrict__ feat, const int* __restrict__ edge_start,
                        const int* __restrict__ csr_src, bf16* __restrict__ agg1,
                        const int* __restrict__ flag)
{
    if (*flag != MODE) return;
    int n = blockIdx.x * 4 + (threadIdx.x >> 6);
    if (n >= N_NODES) return;
    int lane = threadIdx.x & 63;
    int e0 = edge_start[n], e1 = edge_start[n + 1];
    float2 acc = {0.f, 0.f};
    for (int i = e0; i < e1; i++) {
        int s = csr_src[i];
        float2 f = ld2(feat + (size_t)s * IN_DIM, lane);
        acc.x += f.x; acc.y += f.y;
    }
    bf16x2 p;
    p.x = __float2bfloat16(acc.x);
    p.y = __float2bfloat16(acc.y);
    ((bf16x2*)(agg1 + (size_t)n * IN_DIM))[lane] = p;
}

// ---------------------------------------------------------------------------
// Layer-2 gather (full range): aggc[n,0:512] = sum h1[src,0:512]  (bf16 out)
// One wave per node; lane holds 8 columns (16B loads/stores), fp32 register acc.
// ---------------------------------------------------------------------------
__global__ __launch_bounds__(256)
void gather_h_kernel(const bf16* __restrict__ h1, const int* __restrict__ edge_start,
                     const int* __restrict__ csr_src, bf16* __restrict__ aggc)
{
    int n = blockIdx.x * 4 + (threadIdx.x >> 6);
    if (n >= N_NODES) return;
    int lane = threadIdx.x & 63;
    int e0 = edge_start[n], e1 = edge_start[n + 1];
    float acc[8];
#pragma unroll
    for (int j = 0; j < 8; j++) acc[j] = 0.f;
    for (int i = e0; i < e1; i++) {
        int s = csr_src[i];
        float4 r = ((const float4*)(h1 + (size_t)s * HID))[lane];
        const bf16x2* p = (const bf16x2*)&r;
#pragma unroll
        for (int q = 0; q < 4; q++) {
            float2 f = __bfloat1622float2(p[q]);
            acc[2 * q] += f.x; acc[2 * q + 1] += f.y;
        }
    }
    s8v s;
#pragma unroll
    for (int j = 0; j < 8; j++) s[j] = f2bs(acc[j]);
    ((float4*)(aggc + (size_t)n * HID))[lane] = __builtin_bit_cast(float4, s);
}

// ---------------------------------------------------------------------------
// MFMA bf16 GEMM: C[M, 512-stride] = A[M,K](bf16) @ Bt[Ncols,K]^T (+biasf, relu)
// 128x128 block tile, BK=64, 4 waves (2x2 of 64x64), 16x16x32 MFMA.
// POOL=0: store bf16 C (stride 512). POOL=1: grouped atomicAdd into
// hg[n2g[n0+row], col] (n2g sorted). Frag layouts per guide §3 (m89/m91):
//   A: [m=lane&15][k=(lane>>4)*8+j]   C/D: col=lane&15, row=(lane>>4)*4+reg
// ---------------------------------------------------------------------------
template<int POOL>
__global__ __launch_bounds__(256)
void mfma_gemm_kernel(const short* __restrict__ A, const short* __restrict__ Bt,
                      const float* __restrict__ biasf, bf16* __restrict__ Cout,
                      const int* __restrict__ n2g, float* __restrict__ hg,
                      int n0, int M, int K)
{
    __shared__ short As[128][72];   // 64 + 8 pad (2-way bank aliasing = free)
    __shared__ short Bs[128][72];

    const int tid  = threadIdx.x;
    const int lane = tid & 63;
    const int wave = tid >> 6;
    const int wr = wave >> 1, wc = wave & 1;
    const int m  = lane & 15, q = lane >> 4;
    const int row0 = blockIdx.y * 128;
    const int col0 = blockIdx.x * 128;

    f32x4 acc[4][4];
#pragma unroll
    for (int i = 0; i < 4; i++)
#pragma unroll
        for (int j = 0; j < 4; j++) acc[i][j] = {0.f, 0.f, 0.f, 0.f};

    for (int k0 = 0; k0 < K; k0 += 64) {
        // stage A tile: 128 rows x 64 cols bf16; 1024 16B segments
#pragma unroll
        for (int i = 0; i < 4; i++) {
            int seg = tid + i * 256;
            int r = seg >> 3, o = seg & 7;
            int gr = row0 + r;
            float4 v = make_float4(0.f, 0.f, 0.f, 0.f);
            if (gr < M) v = stage8(A + (size_t)gr * K + k0 + o * 8);
            *(float4*)&As[r][o * 8] = v;
        }
        // stage Bt tile (rows = output cols; Bt allocated padded to grid cols)
#pragma unroll
        for (int i = 0; i < 4; i++) {
            int seg = tid + i * 256;
            int r = seg >> 3, o = seg & 7;
            *(float4*)&Bs[r][o * 8] =
                *(const float4*)(Bt + (size_t)(col0 + r) * K + k0 + o * 8);
        }
        __syncthreads();
#pragma unroll
        for (int kq = 0; kq < 2; kq++) {
            s8v av[4], bv[4];
#pragma unroll
            for (int rt = 0; rt < 4; rt++)
                av[rt] = *(const s8v*)&As[wr * 64 + rt * 16 + m][kq * 32 + q * 8];
#pragma unroll
            for (int ct = 0; ct < 4; ct++)
                bv[ct] = *(const s8v*)&Bs[wc * 64 + ct * 16 + m][kq * 32 + q * 8];
#pragma unroll
            for (int rt = 0; rt < 4; rt++)
#pragma unroll
                for (int ct = 0; ct < 4; ct++)
                    acc[rt][ct] = __builtin_amdgcn_mfma_f32_16x16x32_bf16(
                        av[rt], bv[ct], acc[rt][ct], 0, 0, 0);
        }
        __syncthreads();
    }

    // Epilogue
#pragma unroll
    for (int rt = 0; rt < 4; rt++) {
        int rbase = row0 + wr * 64 + rt * 16 + q * 4;
        if (POOL == 0) {
#pragma unroll
            for (int ct = 0; ct < 4; ct++) {
                int col = col0 + wc * 64 + ct * 16 + m;
                float bv = biasf[col];
#pragma unroll
                for (int reg = 0; reg < 4; reg++) {
                    int row = rbase + reg;
                    if (row < M) {
                        float v = acc[rt][ct][reg] + bv;
                        v = v > 0.f ? v : 0.f;
                        Cout[(size_t)row * HID + col] = __float2bfloat16(v);
                    }
                }
            }
        } else {
            int g4[4];
#pragma unroll
            for (int reg = 0; reg < 4; reg++) {
                int row = rbase + reg;
                g4[reg] = (row < M) ? n2g[n0 + row] : -1;
            }
#pragma unroll
            for (int ct = 0; ct < 4; ct++) {
                int col = col0 + wc * 64 + ct * 16 + m;
                float bv = biasf[col];
                float pend = 0.f;
                int gprev = -1;
#pragma unroll
                for (int reg = 0; reg < 4; reg++) {
                    if (g4[reg] < 0) continue;
                    float v = acc[rt][ct][reg] + bv;
                    v = v > 0.f ? v : 0.f;
                    if (g4[reg] != gprev) {
                        if (gprev >= 0)
                            atomicAdd(&hg[(size_t)gprev * HID + col], pend);
                        gprev = g4[reg];
                        pend = 0.f;
                    }
                    pend += v;
                }
                if (gprev >= 0)
                    atomicAdd(&hg[(size_t)gprev * HID + col], pend);
            }
        }
    }
}

// counts[g] = number of nodes in graph g
__global__ __launch_bounds__(256)
void count_nodes_kernel(const int* __restrict__ n2g, float* __restrict__ counts)
{
    int n = blockIdx.x * 256 + threadIdx.x;
    if (n < N_NODES) atomicAdd(&counts[n2g[n]], 1.0f);
}

// xinb[g, c] (bf16, stride 768) = c<512: hg/cnt | c<712: desc | else 0
template<typename FT, int MODE>
__global__ __launch_bounds__(256)
void build_xin_kernel(const float* __restrict__ hg, const float* __restrict__ counts,
                      const FT* __restrict__ desc, bf16* __restrict__ xinb,
                      const int* __restrict__ flag)
{
    if (*flag != MODE) return;
    int idx = blockIdx.x * 256 + threadIdx.x;
    if (idx >= N_GRAPHS * XIN_PAD) return;
    int g = idx / XIN_PAD;
    int c = idx - g * XIN_PAD;
    float v;
    if (c < HID) {
        float cnt = counts[g];
        v = hg[(size_t)g * HID + c] / (cnt > 1.0f ? cnt : 1.0f);
    } else if (c < XIN_DIM) {
        v = ldf(desc, (size_t)g * N_DESC + (c - HID));
    } else {
        v = 0.f;
    }
    xinb[idx] = __float2bfloat16(v);
}

// out[g, c] = x2b[g,:100] @ cw[:,c] + cb[c]; output dtype = FT
template<typename FT, int MODE>
__global__ __launch_bounds__(256)
void final_layer_kernel(const bf16* __restrict__ x2b, const FT* __restrict__ cw,
                        const FT* __restrict__ cb, FT* __restrict__ out,
                        const int* __restrict__ flag)
{
    if (*flag != MODE) return;
    int i = blockIdx.x * 256 + threadIdx.x;
    if (i >= N_GRAPHS * N_CLASSES) return;
    int r = i >> 1, c = i & 1;
    float acc = ldf(cb, c);
    const bf16* x = x2b + (size_t)r * HID;   // stride 512, cols 0..99 valid
#pragma unroll 4
    for (int k = 0; k < MLP2_OUT; k++)
        acc += __bfloat162float(x[k]) * ldf(cw, k * N_CLASSES + c);
    store_out(&out[i], acc);
}

// ---------------------------------------------------------------------------
static inline size_t align_up(size_t x, size_t a) { return (x + a - 1) & ~(a - 1); }

extern "C" void kernel_launch(void* const* d_in, const int* in_sizes, int n_in,
                              void* d_out, int out_size, void* d_ws, size_t ws_size,
                              hipStream_t stream)
{
    const void* features    = d_in[0];
    const void* descriptors = d_in[1];
    const int*  src         = (const int*)d_in[2];
    const int*  dst         = (const int*)d_in[3];
    const int*  node2graph  = (const int*)d_in[4];
    const void* W1          = d_in[5];
    const void* b1          = d_in[6];
    const void* W2          = d_in[7];
    const void* b2          = d_in[8];
    const void* lw1         = d_in[9];
    const void* lb1         = d_in[10];
    const void* lw2         = d_in[11];
    const void* lb2         = d_in[12];
    const void* cw          = d_in[13];
    const void* cb          = d_in[14];
    (void)in_sizes; (void)n_in; (void)out_size; (void)ws_size;

    // ---- Workspace layout (fixed ~218 MB; proven ws >= ~239 MB) ----
    // R_A (102.4 MB): agg1 bf16 [100000,128] -> aggc bf16 [100000,512]
    //                 -> head buffers (xinb @0, x1b @8MB, x2b @16MB)
    // R_B (102.4 MB): h1 bf16 [100000,512]
    char* ws = (char*)d_ws;
    size_t off = 0;
    bf16* agg1 = (bf16*)(ws + off);
    bf16* aggc = (bf16*)(ws + off);
    bf16* xinb = (bf16*)(ws + off);                                // 6.14 MB
    bf16* x1b  = (bf16*)(ws + off + (size_t)8 * 1024 * 1024);      // 4.1 MB
    bf16* x2b  = (bf16*)(ws + off + (size_t)16 * 1024 * 1024);     // 4.1 MB
    off = align_up(off + (size_t)N_NODES * HID * sizeof(bf16), 256);   // 102.4 MB
    bf16* h1 = (bf16*)(ws + off);
    off = align_up(off + (size_t)N_NODES * HID * sizeof(bf16), 256);   // +102.4 MB
    float* hg = (float*)(ws + off);
    off = align_up(off + (size_t)N_GRAPHS * HID * sizeof(float), 256); // +8.19 MB
    float* counts = (float*)(ws + off);
    off = align_up(off + (size_t)N_GRAPHS * sizeof(float), 256);
    int* dflag = (int*)(ws + off);          off = align_up(off + 256, 256);
    int* edge_start = (int*)(ws + off);     off = align_up(off + (N_NODES + 1) * 4, 256);
    int* cursor = (int*)(ws + off);         off = align_up(off + N_NODES * 4, 256);
    int* csr_src = (int*)(ws + off);        off = align_up(off + N_EDGES * 4, 256);
    int* part = (int*)(ws + off);           off = align_up(off + NCHK * 4, 256);
    int* deg = (int*)(ws + off);            off = align_up(off + N_NODES * 4, 256);
    short* W1t  = (short*)(ws + off);       off = align_up(off + (size_t)HID * IN_DIM * 2, 256);
    short* W2t  = (short*)(ws + off);       off = align_up(off + (size_t)HID * HID * 2, 256);
    short* lw1t = (short*)(ws + off);       off = align_up(off + (size_t)512 * XIN_PAD * 2, 256);
    short* lw2t = (short*)(ws + off);       off = align_up(off + (size_t)128 * HID * 2, 256);
    float* b1f  = (float*)(ws + off);       off = align_up(off + 512 * 4, 256);
    float* b2f  = (float*)(ws + off);       off = align_up(off + 512 * 4, 256);
    float* lb1f = (float*)(ws + off);       off = align_up(off + 512 * 4, 256);
    float* lb2f = (float*)(ws + off);       off = align_up(off + 128 * 4, 256);

    // ---- Detect float-tensor dtype (flag: 0=fp32, 1=bf16) ----
    detect_dtype_kernel<<<1, 256, 0, stream>>>(
        (const unsigned*)features, (unsigned)(N_NODES * IN_DIM / 2), dflag);

    // ---- Weight prep (one fused launch per mode; 788096 elements) ----
    {
        int nblk = (788096 + 255) / 256;
        prep_weights_kernel<float, 0><<<nblk, 256, 0, stream>>>(
            (const float*)W1, (const float*)W2, (const float*)lw1, (const float*)lw2,
            (const float*)b1, (const float*)b2, (const float*)lb1, (const float*)lb2,
            W1t, W2t, lw1t, lw2t, b1f, b2f, lb1f, lb2f, dflag);
        prep_weights_kernel<bf16, 1><<<nblk, 256, 0, stream>>>(
            (const bf16*)W1, (const bf16*)W2, (const bf16*)lw1, (const bf16*)lw2,
            (const bf16*)b1, (const bf16*)b2, (const bf16*)lb1, (const bf16*)lb2,
            W1t, W2t, lw1t, lw2t, b1f, b2f, lb1f, lb2f, dflag);
    }

    // ---- Pool setup ----
    hipMemsetAsync(hg, 0, (size_t)N_GRAPHS * HID * sizeof(float), stream);
    hipMemsetAsync(counts, 0, (size_t)N_GRAPHS * sizeof(float), stream);
    count_nodes_kernel<<<(N_NODES + 255) / 256, 256, 0, stream>>>(node2graph, counts);

    // ---- CSR build (counting sort by dst) ----
    hipMemsetAsync(deg, 0, N_NODES * 4, stream);
    deg_kernel<<<(N_EDGES + 255) / 256, 256, 0, stream>>>(dst, deg);
    scan_partial_kernel<<<NCHK, 256, 0, stream>>>(deg, part);
    scan_parts_kernel<<<1, 1, 0, stream>>>(part, edge_start);
    scan_final_kernel<<<NCHK, 256, 0, stream>>>(deg, part, edge_start);
    cursor_kernel<<<(N_NODES + 255) / 256, 256, 0, stream>>>(edge_start, cursor);
    fill_kernel<<<(N_EDGES + 255) / 256, 256, 0, stream>>>(src, dst, cursor, csr_src);

    // ---- Layer 1: gather -> agg1 (bf16), MFMA GEMM -> h1 (bf16) ----
    gather_feat_kernel<float, 0><<<N_NODES / 4, 256, 0, stream>>>(
        (const float*)features, edge_start, csr_src, agg1, dflag);
    gather_feat_kernel<bf16, 1><<<N_NODES / 4, 256, 0, stream>>>(
        (const bf16*)features, edge_start, csr_src, agg1, dflag);
    {
        dim3 grid(HID / 128, (N_NODES + 127) / 128);
        mfma_gemm_kernel<0><<<grid, 256, 0, stream>>>(
            (const short*)agg1, W1t, b1f, h1, nullptr, nullptr, 0, N_NODES, IN_DIM);
    }

    // ---- Layer 2 (single pass): gather h1 -> aggc (bf16, clobbers agg1),
    //      MFMA GEMM + fused mean-pool numerator into hg ----
    gather_h_kernel<<<N_NODES / 4, 256, 0, stream>>>(h1, edge_start, csr_src, aggc);
    {
        dim3 grid(HID / 128, (N_NODES + 127) / 128);
        mfma_gemm_kernel<1><<<grid, 256, 0, stream>>>(
            (const short*)aggc, W2t, b2f, nullptr, node2graph, hg, 0, N_NODES, HID);
    }

    // ---- Head (all MFMA; padded-K trick makes layers chain) ----
    {
        int nthr = (N_GRAPHS * XIN_PAD + 255) / 256;
        build_xin_kernel<float, 0><<<nthr, 256, 0, stream>>>(
            hg, counts, (const float*)descriptors, xinb, dflag);
        build_xin_kernel<bf16, 1><<<nthr, 256, 0, stream>>>(
            hg, counts, (const bf16*)descriptors, xinb, dflag);
    }
    {   // x1b[4000,512] = relu(xinb[4000,768] @ lw1t^T + lb1f); cols 500..511 = 0
        dim3 grid(4, (N_GRAPHS + 127) / 128);
        mfma_gemm_kernel<0><<<grid, 256, 0, stream>>>(
            (const short*)xinb, lw1t, lb1f, x1b, nullptr, nullptr, 0, N_GRAPHS, XIN_PAD);
    }
    {   // x2b cols 0..127 (stride 512) = relu(x1b @ lw2t^T + lb2f)
        dim3 grid(1, (N_GRAPHS + 127) / 128);
        mfma_gemm_kernel<0><<<grid, 256, 0, stream>>>(
            (const short*)x1b, lw2t, lb2f, x2b, nullptr, nullptr, 0, N_GRAPHS, HID);
    }
    {
        int nthr = (N_GRAPHS * N_CLASSES + 255) / 256;
        final_layer_kernel<float, 0><<<nthr, 256, 0, stream>>>(
            x2b, (const float*)cw, (const float*)cb, (float*)d_out, dflag);
        final_layer_kernel<bf16, 1><<<nthr, 256, 0, stream>>>(
            x2b, (const bf16*)cw, (const bf16*)cb, (bf16*)d_out, dflag);
    }
}

// Round 9
// 583.471 us; speedup vs baseline: 12.7573x; 1.1378x over previous
//
#include <hip/hip_runtime.h>
#include <hip/hip_bf16.h>

// Problem constants (from reference)
#define N_NODES  100000
#define N_EDGES  400000
#define N_GRAPHS 4000
#define IN_DIM   128
#define HID      512
#define N_DESC   200
#define N_CLASSES 2
#define MLP1_OUT 500
#define MLP2_OUT 100
#define XIN_DIM  (HID + N_DESC)   // 712
#define XIN_PAD  768              // K padded to multiple of 64

#define SCAN_CHUNK 1024
#define NCHK ((N_NODES + SCAN_CHUNK - 1) / SCAN_CHUNK)   // 98

typedef __hip_bfloat16  bf16;
typedef __hip_bfloat162 bf16x2;
typedef short s8v  __attribute__((ext_vector_type(8)));   // 8 bf16 (4 VGPRs)
typedef float f32x4 __attribute__((ext_vector_type(4)));

// ---------------------------------------------------------------------------
// Dtype-generic helpers (FT = float or bf16), all produce fp32.
// ---------------------------------------------------------------------------
__device__ __forceinline__ float ldf(const float* p, size_t i) { return p[i]; }
__device__ __forceinline__ float ldf(const bf16* p, size_t i)  { return __bfloat162float(p[i]); }

__device__ __forceinline__ float2 ld2(const float* p, int i) { return ((const float2*)p)[i]; }
__device__ __forceinline__ float2 ld2(const bf16* p, int i)  {
    return __bfloat1622float2(((const bf16x2*)p)[i]);
}

__device__ __forceinline__ void store_out(float* p, float v) { *p = v; }
__device__ __forceinline__ void store_out(bf16* p, float v)  { *p = __float2bfloat16(v); }

__device__ __forceinline__ short f2bs(float x) {
    bf16 h = __float2bfloat16(x);
    return __builtin_bit_cast(short, h);
}

// async global->LDS, 16B per lane; LDS dest = wave-uniform base + lane*16
__device__ __forceinline__ void gld16(const short* g, short* l) {
    __builtin_amdgcn_global_load_lds(
        (const __attribute__((address_space(1))) unsigned int*)g,
        (__attribute__((address_space(3))) unsigned int*)l, 16, 0, 0);
}

// ---------------------------------------------------------------------------
// Runtime dtype detection (flag: 0=fp32, 1=bf16); see round-5 notes.
// ---------------------------------------------------------------------------
__global__ __launch_bounds__(256)
void detect_dtype_kernel(const unsigned* __restrict__ words, unsigned nw,
                         int* __restrict__ flag)
{
    __shared__ int s_cnt;
    if (threadIdx.x == 0) s_cnt = 0;
    __syncthreads();
    const int SAMPLES = 2048;
    int sane = 0;
    for (int i = threadIdx.x; i < SAMPLES; i += 256) {
        size_t idx = (size_t)(((unsigned long long)i * 2654435761ull) % nw);
        unsigned w = words[idx];
        float f = __uint_as_float((w & 0xFFFFu) << 16);
        float a = fabsf(f);
        if (f == 0.0f || (a > 1e-8f && a < 1e8f)) sane++;
    }
    atomicAdd(&s_cnt, sane);
    __syncthreads();
    if (threadIdx.x == 0) *flag = (s_cnt * 10 > SAMPLES * 6) ? 1 : 0;
}

// ---------------------------------------------------------------------------
// Fused weight prep (dual-mode): weights -> transposed bf16 [N][K] (zero-pad),
// biases -> fp32 (zero-pad). Segments: W1t 65536 | W2t 262144 | lw1t 393216 |
// lw2t 65536 | b1f 512 | b2f 512 | lb1f 512 | lb2f 128  (total 788096)
// ---------------------------------------------------------------------------
template<typename FT, int MODE>
__global__ __launch_bounds__(256)
void prep_weights_kernel(const FT* __restrict__ W1, const FT* __restrict__ W2,
                         const FT* __restrict__ lw1, const FT* __restrict__ lw2,
                         const FT* __restrict__ b1, const FT* __restrict__ b2,
                         const FT* __restrict__ lb1, const FT* __restrict__ lb2,
                         short* __restrict__ W1t, short* __restrict__ W2t,
                         short* __restrict__ lw1t, short* __restrict__ lw2t,
                         float* __restrict__ b1f, float* __restrict__ b2f,
                         float* __restrict__ lb1f, float* __restrict__ lb2f,
                         const int* __restrict__ flag)
{
    if (*flag != MODE) return;
    int i = blockIdx.x * 256 + threadIdx.x;
    if (i < 65536) {            // W1t [512][128] <- W1 [128,512]
        int n = i >> 7, k = i & 127;
        W1t[i] = f2bs(ldf(W1, (size_t)k * HID + n));
        return;
    }
    i -= 65536;
    if (i < 262144) {           // W2t [512][512] <- W2 [512,512]
        int n = i >> 9, k = i & 511;
        W2t[i] = f2bs(ldf(W2, (size_t)k * HID + n));
        return;
    }
    i -= 262144;
    if (i < 393216) {           // lw1t [512][768] <- lw1 [712,500], zero-pad
        int n = i / XIN_PAD, k = i - n * XIN_PAD;
        lw1t[i] = (n < MLP1_OUT && k < XIN_DIM)
                      ? f2bs(ldf(lw1, (size_t)k * MLP1_OUT + n)) : (short)0;
        return;
    }
    i -= 393216;
    if (i < 65536) {            // lw2t [128][512] <- lw2 [500,100], zero-pad
        int n = i >> 9, k = i & 511;
        lw2t[i] = (n < MLP2_OUT && k < MLP1_OUT)
                      ? f2bs(ldf(lw2, (size_t)k * MLP2_OUT + n)) : (short)0;
        return;
    }
    i -= 65536;
    if (i < 512) { b1f[i] = ldf(b1, i); return; }
    i -= 512;
    if (i < 512) { b2f[i] = ldf(b2, i); return; }
    i -= 512;
    if (i < 512) { lb1f[i] = (i < MLP1_OUT) ? ldf(lb1, i) : 0.f; return; }
    i -= 512;
    if (i < 128) { lb2f[i] = (i < MLP2_OUT) ? ldf(lb2, i) : 0.f; return; }
}

// ---------------------------------------------------------------------------
// CSR build: deg histogram -> two-level exclusive scan -> fill
// ---------------------------------------------------------------------------
__global__ __launch_bounds__(256)
void deg_kernel(const int* __restrict__ dst, int* __restrict__ deg)
{
    int e = blockIdx.x * 256 + threadIdx.x;
    if (e < N_EDGES) atomicAdd(&deg[dst[e]], 1);
}

__global__ __launch_bounds__(256)
void scan_partial_kernel(const int* __restrict__ deg, int* __restrict__ part)
{
    int c = blockIdx.x, t = threadIdx.x;
    int i0 = c * SCAN_CHUNK + t * 4;
    int s = 0;
#pragma unroll
    for (int j = 0; j < 4; j++) {
        int i = i0 + j;
        if (i < N_NODES) s += deg[i];
    }
    __shared__ int red[256];
    red[t] = s;
    __syncthreads();
    for (int off = 128; off > 0; off >>= 1) {
        if (t < off) red[t] += red[t + off];
        __syncthreads();
    }
    if (t == 0) part[c] = red[0];
}

__global__ void scan_parts_kernel(int* __restrict__ part, int* __restrict__ edge_start)
{
    int run = 0;
    for (int c = 0; c < NCHK; c++) { int v = part[c]; part[c] = run; run += v; }
    edge_start[N_NODES] = run;
}

__global__ __launch_bounds__(256)
void scan_final_kernel(const int* __restrict__ deg, const int* __restrict__ part,
                       int* __restrict__ edge_start)
{
    int c = blockIdx.x, t = threadIdx.x;
    int i0 = c * SCAN_CHUNK + t * 4;
    int d[4];
    int tsum = 0;
#pragma unroll
    for (int j = 0; j < 4; j++) {
        int i = i0 + j;
        d[j] = (i < N_NODES) ? deg[i] : 0;
        tsum += d[j];
    }
    __shared__ int s[256];
    s[t] = tsum;
    __syncthreads();
    for (int off = 1; off < 256; off <<= 1) {
        int v = (t >= off) ? s[t - off] : 0;
        __syncthreads();
        s[t] += v;
        __syncthreads();
    }
    int run = part[c] + s[t] - tsum;
#pragma unroll
    for (int j = 0; j < 4; j++) {
        int i = i0 + j;
        if (i < N_NODES) { edge_start[i] = run; run += d[j]; }
    }
}

__global__ __launch_bounds__(256)
void cursor_kernel(const int* __restrict__ edge_start, int* __restrict__ cursor)
{
    int n = blockIdx.x * 256 + threadIdx.x;
    if (n < N_NODES) cursor[n] = edge_start[n];
}

__global__ __launch_bounds__(256)
void fill_kernel(const int* __restrict__ src, const int* __restrict__ dst,
                 int* __restrict__ cursor, int* __restrict__ csr_src)
{
    int e = blockIdx.x * 256 + threadIdx.x;
    if (e >= N_EDGES) return;
    int p = atomicAdd(&cursor[dst[e]], 1);
    csr_src[p] = src[e];
}

// gstart[g] = first node index with node2graph >= g (node2graph sorted)
__global__ __launch_bounds__(256)
void gstart_kernel(const int* __restrict__ n2g, int* __restrict__ gstart)
{
    int n = blockIdx.x * 256 + threadIdx.x;
    if (n > N_NODES) return;
    if (n == N_NODES) {
        int last = n2g[N_NODES - 1];
        for (int g = last + 1; g <= N_GRAPHS; g++) gstart[g] = N_NODES;
        return;
    }
    int v = n2g[n];
    int prev = (n == 0) ? -1 : n2g[n - 1];
    for (int g = prev + 1; g <= v; g++) gstart[g] = n;
}

// ---------------------------------------------------------------------------
// Layer-1 gather: agg1[n,0:128] = sum_{e: dst=n} feat[src[e],0:128]  (bf16 out)
// ---------------------------------------------------------------------------
template<typename FT, int MODE>
__global__ __launch_bounds__(256)
void gather_feat_kernel(const FT* __restrict__ feat, const int* __restrict__ edge_start,
                        const int* __restrict__ csr_src, bf16* __restrict__ agg1,
                        const int* __restrict__ flag)
{
    if (*flag != MODE) return;
    int n = blockIdx.x * 4 + (threadIdx.x >> 6);
    if (n >= N_NODES) return;
    int lane = threadIdx.x & 63;
    int e0 = edge_start[n], e1 = edge_start[n + 1];
    float2 acc = {0.f, 0.f};
    for (int i = e0; i < e1; i++) {
        int s = csr_src[i];
        float2 f = ld2(feat + (size_t)s * IN_DIM, lane);
        acc.x += f.x; acc.y += f.y;
    }
    bf16x2 p;
    p.x = __float2bfloat16(acc.x);
    p.y = __float2bfloat16(acc.y);
    ((bf16x2*)(agg1 + (size_t)n * IN_DIM))[lane] = p;
}

// ---------------------------------------------------------------------------
// Layer-2 gather: aggc[n,0:512] = sum h1[src,0:512]  (bf16 out, fp32 reg acc)
// ---------------------------------------------------------------------------
__global__ __launch_bounds__(256)
void gather_h_kernel(const bf16* __restrict__ h1, const int* __restrict__ edge_start,
                     const int* __restrict__ csr_src, bf16* __restrict__ aggc)
{
    int n = blockIdx.x * 4 + (threadIdx.x >> 6);
    if (n >= N_NODES) return;
    int lane = threadIdx.x & 63;
    int e0 = edge_start[n], e1 = edge_start[n + 1];
    float acc[8];
#pragma unroll
    for (int j = 0; j < 8; j++) acc[j] = 0.f;
    for (int i = e0; i < e1; i++) {
        int s = csr_src[i];
        float4 r = ((const float4*)(h1 + (size_t)s * HID))[lane];
        const bf16x2* p = (const bf16x2*)&r;
#pragma unroll
        for (int q = 0; q < 4; q++) {
            float2 f = __bfloat1622float2(p[q]);
            acc[2 * q] += f.x; acc[2 * q + 1] += f.y;
        }
    }
    s8v s;
#pragma unroll
    for (int j = 0; j < 8; j++) s[j] = f2bs(acc[j]);
    ((float4*)(aggc + (size_t)n * HID))[lane] = __builtin_bit_cast(float4, s);
}

// ---------------------------------------------------------------------------
// MFMA bf16 GEMM (m97-style): C[M,512-stride] = relu(A[M,K] @ Bt[N,K]^T + b)
// 128x128 tile, BK=64, 256 thr (4 waves, 2x2 of 64x64), 16x16x32 MFMA,
// global_load_lds(16B) staging into unpadded LDS [128][64].
// Frag layouts per guide §3 (m89/m91): A:[m=lane&15][k=(lane>>4)*8+j],
// C/D: col=lane&15, row=(lane>>4)*4+reg.
// ---------------------------------------------------------------------------
__global__ __launch_bounds__(256)
void mfma_gemm_kernel(const short* __restrict__ A, const short* __restrict__ Bt,
                      const float* __restrict__ biasf, bf16* __restrict__ Cout,
                      int M, int K)
{
    __shared__ short As[128 * 64];   // 16 KB
    __shared__ short Bs[128 * 64];   // 16 KB

    const int tid  = threadIdx.x;
    const int lane = tid & 63;
    const int w    = tid >> 6;
    const int wr = w >> 1, wc = w & 1;
    const int m  = lane & 15, q = lane >> 4;
    const int row0 = blockIdx.y * 128;
    const int col0 = blockIdx.x * 128;

    // Staging pointers: 4 A-chunks + 4 B-chunks per wave (1 KB each).
    // Chunk c covers rows (w*4+c)*8 .. +7; lane l -> row +(l>>3), col (l&7)*8.
    const int dr = lane >> 3;
    const int dc = (lane & 7) * 8;
    const short* ga[4];
    const short* gb[4];
    short* la[4];
    short* lb[4];
#pragma unroll
    for (int c = 0; c < 4; c++) {
        int r = (w * 4 + c) * 8 + dr;
        ga[c] = A  + (size_t)(row0 + r) * K + dc;   // OOB rows: harmless in-ws garbage
        gb[c] = Bt + (size_t)(col0 + r) * K + dc;   // Bt always padded to grid cols
        la[c] = As + (w * 4 + c) * 512;
        lb[c] = Bs + (w * 4 + c) * 512;
    }

    f32x4 acc[4][4];
#pragma unroll
    for (int i = 0; i < 4; i++)
#pragma unroll
        for (int j = 0; j < 4; j++) acc[i][j] = {0.f, 0.f, 0.f, 0.f};

    for (int k0 = 0; k0 < K; k0 += 64) {
#pragma unroll
        for (int c = 0; c < 4; c++) gld16(ga[c], la[c]);
#pragma unroll
        for (int c = 0; c < 4; c++) gld16(gb[c], lb[c]);
#pragma unroll
        for (int c = 0; c < 4; c++) { ga[c] += 64; gb[c] += 64; }
        __syncthreads();   // compiler emits s_waitcnt vmcnt(0) before barrier

#pragma unroll
        for (int kq = 0; kq < 2; kq++) {
            s8v av[4], bv[4];
#pragma unroll
            for (int rt = 0; rt < 4; rt++)
                av[rt] = *(const s8v*)&As[(wr * 64 + rt * 16 + m) * 64 + kq * 32 + q * 8];
#pragma unroll
            for (int ct = 0; ct < 4; ct++)
                bv[ct] = *(const s8v*)&Bs[(wc * 64 + ct * 16 + m) * 64 + kq * 32 + q * 8];
#pragma unroll
            for (int rt = 0; rt < 4; rt++)
#pragma unroll
                for (int ct = 0; ct < 4; ct++)
                    acc[rt][ct] = __builtin_amdgcn_mfma_f32_16x16x32_bf16(
                        av[rt], bv[ct], acc[rt][ct], 0, 0, 0);
        }
        __syncthreads();
    }

    // Epilogue: bias + relu, plain bf16 store (stride 512)
#pragma unroll
    for (int rt = 0; rt < 4; rt++) {
        int rbase = row0 + wr * 64 + rt * 16 + q * 4;
#pragma unroll
        for (int ct = 0; ct < 4; ct++) {
            int col = col0 + wc * 64 + ct * 16 + m;
            float bv = biasf[col];
#pragma unroll
            for (int reg = 0; reg < 4; reg++) {
                int row = rbase + reg;
                if (row < M) {
                    float v = acc[rt][ct][reg] + bv;
                    v = v > 0.f ? v : 0.f;
                    Cout[(size_t)row * HID + col] = __float2bfloat16(v);
                }
            }
        }
    }
}

// ---------------------------------------------------------------------------
// Graph mean-pool numerator, NO atomics: wave per graph (nodes contiguous).
// hg[g, :] = sum_{n in [gstart[g], gstart[g+1])} h2[n, :]
// ---------------------------------------------------------------------------
__global__ __launch_bounds__(256)
void pool_graph_kernel(const bf16* __restrict__ h2, const int* __restrict__ gstart,
                       float* __restrict__ hg)
{
    int g = blockIdx.x * 4 + (threadIdx.x >> 6);
    if (g >= N_GRAPHS) return;
    int lane = threadIdx.x & 63;
    int s0 = gstart[g], s1 = gstart[g + 1];
    float acc[8];
#pragma unroll
    for (int j = 0; j < 8; j++) acc[j] = 0.f;
    for (int n = s0; n < s1; n++) {
        float4 r = ((const float4*)(h2 + (size_t)n * HID))[lane];
        const bf16x2* p = (const bf16x2*)&r;
#pragma unroll
        for (int q = 0; q < 4; q++) {
            float2 f = __bfloat1622float2(p[q]);
            acc[2 * q] += f.x; acc[2 * q + 1] += f.y;
        }
    }
    float* orow = hg + (size_t)g * HID + lane * 8;
    ((float4*)orow)[0] = make_float4(acc[0], acc[1], acc[2], acc[3]);
    ((float4*)orow)[1] = make_float4(acc[4], acc[5], acc[6], acc[7]);
}

// xinb[g, c] (bf16, stride 768) = c<512: hg/cnt | c<712: desc | else 0
template<typename FT, int MODE>
__global__ __launch_bounds__(256)
void build_xin_kernel(const float* __restrict__ hg, const int* __restrict__ gstart,
                      const FT* __restrict__ desc, bf16* __restrict__ xinb,
                      const int* __restrict__ flag)
{
    if (*flag != MODE) return;
    int idx = blockIdx.x * 256 + threadIdx.x;
    if (idx >= N_GRAPHS * XIN_PAD) return;
    int g = idx / XIN_PAD;
    int c = idx - g * XIN_PAD;
    float v;
    if (c < HID) {
        float cnt = (float)(gstart[g + 1] - gstart[g]);
        v = hg[(size_t)g * HID + c] / (cnt > 1.0f ? cnt : 1.0f);
    } else if (c < XIN_DIM) {
        v = ldf(desc, (size_t)g * N_DESC + (c - HID));
    } else {
        v = 0.f;
    }
    xinb[idx] = __float2bfloat16(v);
}

// out[g, c] = x2b[g,:100] @ cw[:,c] + cb[c]; output dtype = FT
template<typename FT, int MODE>
__global__ __launch_bounds__(256)
void final_layer_kernel(const bf16* __restrict__ x2b, const FT* __restrict__ cw,
                        const FT* __restrict__ cb, FT* __restrict__ out,
                        const int* __restrict__ flag)
{
    if (*flag != MODE) return;
    int i = blockIdx.x * 256 + threadIdx.x;
    if (i >= N_GRAPHS * N_CLASSES) return;
    int r = i >> 1, c = i & 1;
    float acc = ldf(cb, c);
    const bf16* x = x2b + (size_t)r * HID;   // stride 512, cols 0..99 valid
#pragma unroll 4
    for (int k = 0; k < MLP2_OUT; k++)
        acc += __bfloat162float(x[k]) * ldf(cw, k * N_CLASSES + c);
    store_out(&out[i], acc);
}

// ---------------------------------------------------------------------------
static inline size_t align_up(size_t x, size_t a) { return (x + a - 1) & ~(a - 1); }

extern "C" void kernel_launch(void* const* d_in, const int* in_sizes, int n_in,
                              void* d_out, int out_size, void* d_ws, size_t ws_size,
                              hipStream_t stream)
{
    const void* features    = d_in[0];
    const void* descriptors = d_in[1];
    const int*  src         = (const int*)d_in[2];
    const int*  dst         = (const int*)d_in[3];
    const int*  node2graph  = (const int*)d_in[4];
    const void* W1          = d_in[5];
    const void* b1          = d_in[6];
    const void* W2          = d_in[7];
    const void* b2          = d_in[8];
    const void* lw1         = d_in[9];
    const void* lb1         = d_in[10];
    const void* lw2         = d_in[11];
    const void* lb2         = d_in[12];
    const void* cw          = d_in[13];
    const void* cb          = d_in[14];
    (void)in_sizes; (void)n_in; (void)out_size; (void)ws_size;

    // ---- Workspace layout (fixed ~218 MB; proven ws >= ~239 MB) ----
    // R_A (102.4 MB): agg1 bf16 [100000,128] -> aggc bf16 [100000,512]
    //                 -> head buffers (xinb @0, x1b @8MB, x2b @16MB)
    // R_B (102.4 MB): h1 bf16 [100000,512] -> h2 bf16 [100000,512]
    char* ws = (char*)d_ws;
    size_t off = 0;
    bf16* agg1 = (bf16*)(ws + off);
    bf16* aggc = (bf16*)(ws + off);
    bf16* xinb = (bf16*)(ws + off);
    bf16* x1b  = (bf16*)(ws + off + (size_t)8 * 1024 * 1024);
    bf16* x2b  = (bf16*)(ws + off + (size_t)16 * 1024 * 1024);
    off = align_up(off + (size_t)N_NODES * HID * sizeof(bf16), 256);   // 102.4 MB
    bf16* h1 = (bf16*)(ws + off);
    bf16* h2 = (bf16*)(ws + off);   // h1 dead after gather_h -> reuse for h2
    off = align_up(off + (size_t)N_NODES * HID * sizeof(bf16), 256);   // +102.4 MB
    float* hg = (float*)(ws + off);
    off = align_up(off + (size_t)N_GRAPHS * HID * sizeof(float), 256); // +8.19 MB
    int* dflag = (int*)(ws + off);          off = align_up(off + 256, 256);
    int* edge_start = (int*)(ws + off);     off = align_up(off + (N_NODES + 1) * 4, 256);
    int* cursor = (int*)(ws + off);         off = align_up(off + N_NODES * 4, 256);
    int* csr_src = (int*)(ws + off);        off = align_up(off + N_EDGES * 4, 256);
    int* part = (int*)(ws + off);           off = align_up(off + NCHK * 4, 256);
    int* deg = (int*)(ws + off);            off = align_up(off + N_NODES * 4, 256);
    int* gstart = (int*)(ws + off);         off = align_up(off + (N_GRAPHS + 1) * 4, 256);
    short* W1t  = (short*)(ws + off);       off = align_up(off + (size_t)HID * IN_DIM * 2, 256);
    short* W2t  = (short*)(ws + off);       off = align_up(off + (size_t)HID * HID * 2, 256);
    short* lw1t = (short*)(ws + off);       off = align_up(off + (size_t)512 * XIN_PAD * 2, 256);
    short* lw2t = (short*)(ws + off);       off = align_up(off + (size_t)128 * HID * 2, 256);
    float* b1f  = (float*)(ws + off);       off = align_up(off + 512 * 4, 256);
    float* b2f  = (float*)(ws + off);       off = align_up(off + 512 * 4, 256);
    float* lb1f = (float*)(ws + off);       off = align_up(off + 512 * 4, 256);
    float* lb2f = (float*)(ws + off);       off = align_up(off + 128 * 4, 256);

    // ---- Detect float-tensor dtype (flag: 0=fp32, 1=bf16) ----
    detect_dtype_kernel<<<1, 256, 0, stream>>>(
        (const unsigned*)features, (unsigned)(N_NODES * IN_DIM / 2), dflag);

    // ---- Weight prep (one fused launch per mode) ----
    {
        int nblk = (788096 + 255) / 256;
        prep_weights_kernel<float, 0><<<nblk, 256, 0, stream>>>(
            (const float*)W1, (const float*)W2, (const float*)lw1, (const float*)lw2,
            (const float*)b1, (const float*)b2, (const float*)lb1, (const float*)lb2,
            W1t, W2t, lw1t, lw2t, b1f, b2f, lb1f, lb2f, dflag);
        prep_weights_kernel<bf16, 1><<<nblk, 256, 0, stream>>>(
            (const bf16*)W1, (const bf16*)W2, (const bf16*)lw1, (const bf16*)lw2,
            (const bf16*)b1, (const bf16*)b2, (const bf16*)lb1, (const bf16*)lb2,
            W1t, W2t, lw1t, lw2t, b1f, b2f, lb1f, lb2f, dflag);
    }

    // ---- CSR build (counting sort by dst) + graph ranges ----
    hipMemsetAsync(deg, 0, N_NODES * 4, stream);
    deg_kernel<<<(N_EDGES + 255) / 256, 256, 0, stream>>>(dst, deg);
    scan_partial_kernel<<<NCHK, 256, 0, stream>>>(deg, part);
    scan_parts_kernel<<<1, 1, 0, stream>>>(part, edge_start);
    scan_final_kernel<<<NCHK, 256, 0, stream>>>(deg, part, edge_start);
    cursor_kernel<<<(N_NODES + 255) / 256, 256, 0, stream>>>(edge_start, cursor);
    fill_kernel<<<(N_EDGES + 255) / 256, 256, 0, stream>>>(src, dst, cursor, csr_src);
    gstart_kernel<<<(N_NODES + 256) / 256, 256, 0, stream>>>(node2graph, gstart);

    // ---- Layer 1: gather -> agg1 (bf16), MFMA GEMM -> h1 (bf16) ----
    gather_feat_kernel<float, 0><<<N_NODES / 4, 256, 0, stream>>>(
        (const float*)features, edge_start, csr_src, agg1, dflag);
    gather_feat_kernel<bf16, 1><<<N_NODES / 4, 256, 0, stream>>>(
        (const bf16*)features, edge_start, csr_src, agg1, dflag);
    {
        dim3 grid(HID / 128, (N_NODES + 127) / 128);
        mfma_gemm_kernel<<<grid, 256, 0, stream>>>(
            (const short*)agg1, W1t, b1f, h1, N_NODES, IN_DIM);
    }

    // ---- Layer 2: gather h1 -> aggc (bf16), MFMA GEMM -> h2, pool (no atomics)
    gather_h_kernel<<<N_NODES / 4, 256, 0, stream>>>(h1, edge_start, csr_src, aggc);
    {
        dim3 grid(HID / 128, (N_NODES + 127) / 128);
        mfma_gemm_kernel<<<grid, 256, 0, stream>>>(
            (const short*)aggc, W2t, b2f, h2, N_NODES, HID);
    }
    pool_graph_kernel<<<N_GRAPHS / 4, 256, 0, stream>>>(h2, gstart, hg);

    // ---- Head (all MFMA; padded-K chaining) ----
    {
        int nthr = (N_GRAPHS * XIN_PAD + 255) / 256;
        build_xin_kernel<float, 0><<<nthr, 256, 0, stream>>>(
            hg, gstart, (const float*)descriptors, xinb, dflag);
        build_xin_kernel<bf16, 1><<<nthr, 256, 0, stream>>>(
            hg, gstart, (const bf16*)descriptors, xinb, dflag);
    }
    {   // x1b[4000,512] = relu(xinb[4000,768] @ lw1t^T + lb1f)
        dim3 grid(4, (N_GRAPHS + 127) / 128);
        mfma_gemm_kernel<<<grid, 256, 0, stream>>>(
            (const short*)xinb, lw1t, lb1f, x1b, N_GRAPHS, XIN_PAD);
    }
    {   // x2b cols 0..127 (stride 512) = relu(x1b @ lw2t^T + lb2f)
        dim3 grid(1, (N_GRAPHS + 127) / 128);
        mfma_gemm_kernel<<<grid, 256, 0, stream>>>(
            (const short*)x1b, lw2t, lb2f, x2b, N_GRAPHS, HID);
    }
    {
        int nthr = (N_GRAPHS * N_CLASSES + 255) / 256;
        final_layer_kernel<float, 0><<<nthr, 256, 0, stream>>>(
            x2b, (const float*)cw, (const float*)cb, (float*)d_out, dflag);
        final_layer_kernel<bf16, 1><<<nthr, 256, 0, stream>>>(
            x2b, (const bf16*)cw, (const bf16*)cb, (bf16*)d_out, dflag);
    }
}

// Round 10
// 549.772 us; speedup vs baseline: 13.5393x; 1.0613x over previous
//
#include <hip/hip_runtime.h>
#include <hip/hip_bf16.h>

// Problem constants (from reference)
#define N_NODES  100000
#define N_EDGES  400000
#define N_GRAPHS 4000
#define IN_DIM   128
#define HID      512
#define N_DESC   200
#define N_CLASSES 2
#define MLP1_OUT 500
#define MLP2_OUT 100
#define XIN_DIM  (HID + N_DESC)   // 712
#define XIN_PAD  768              // K padded to multiple of 64

#define SCAN_CHUNK 1024
#define NCHK ((N_NODES + SCAN_CHUNK - 1) / SCAN_CHUNK)   // 98

typedef __hip_bfloat16  bf16;
typedef __hip_bfloat162 bf16x2;
typedef short s8v  __attribute__((ext_vector_type(8)));   // 8 bf16 (4 VGPRs)
typedef float f32x4 __attribute__((ext_vector_type(4)));

// ---------------------------------------------------------------------------
// Dtype-generic helpers (FT = float or bf16), all produce fp32.
// ---------------------------------------------------------------------------
__device__ __forceinline__ float ldf(const float* p, size_t i) { return p[i]; }
__device__ __forceinline__ float ldf(const bf16* p, size_t i)  { return __bfloat162float(p[i]); }

__device__ __forceinline__ float2 ld2(const float* p, int i) { return ((const float2*)p)[i]; }
__device__ __forceinline__ float2 ld2(const bf16* p, int i)  {
    return __bfloat1622float2(((const bf16x2*)p)[i]);
}

__device__ __forceinline__ void store_out(float* p, float v) { *p = v; }
__device__ __forceinline__ void store_out(bf16* p, float v)  { *p = __float2bfloat16(v); }

__device__ __forceinline__ short f2bs(float x) {
    bf16 h = __float2bfloat16(x);
    return __builtin_bit_cast(short, h);
}

// async global->LDS, 16B per lane; LDS dest = wave-uniform base + lane*16
__device__ __forceinline__ void gld16(const short* g, short* l) {
    __builtin_amdgcn_global_load_lds(
        (const __attribute__((address_space(1))) unsigned int*)g,
        (__attribute__((address_space(3))) unsigned int*)l, 16, 0, 0);
}

// ---------------------------------------------------------------------------
// Runtime dtype detection (flag: 0=fp32, 1=bf16); see round-5 notes.
// ---------------------------------------------------------------------------
__global__ __launch_bounds__(256)
void detect_dtype_kernel(const unsigned* __restrict__ words, unsigned nw,
                         int* __restrict__ flag)
{
    __shared__ int s_cnt;
    if (threadIdx.x == 0) s_cnt = 0;
    __syncthreads();
    const int SAMPLES = 2048;
    int sane = 0;
    for (int i = threadIdx.x; i < SAMPLES; i += 256) {
        size_t idx = (size_t)(((unsigned long long)i * 2654435761ull) % nw);
        unsigned w = words[idx];
        float f = __uint_as_float((w & 0xFFFFu) << 16);
        float a = fabsf(f);
        if (f == 0.0f || (a > 1e-8f && a < 1e8f)) sane++;
    }
    atomicAdd(&s_cnt, sane);
    __syncthreads();
    if (threadIdx.x == 0) *flag = (s_cnt * 10 > SAMPLES * 6) ? 1 : 0;
}

// ---------------------------------------------------------------------------
// Fused weight prep (dual-mode): weights -> transposed bf16 [N][K] (zero-pad),
// biases -> fp32 (zero-pad). Segments: W1t 65536 | W2t 262144 | lw1t 393216 |
// lw2t 65536 | b1f 512 | b2f 512 | lb1f 512 | lb2f 128  (total 788096)
// ---------------------------------------------------------------------------
template<typename FT, int MODE>
__global__ __launch_bounds__(256)
void prep_weights_kernel(const FT* __restrict__ W1, const FT* __restrict__ W2,
                         const FT* __restrict__ lw1, const FT* __restrict__ lw2,
                         const FT* __restrict__ b1, const FT* __restrict__ b2,
                         const FT* __restrict__ lb1, const FT* __restrict__ lb2,
                         short* __restrict__ W1t, short* __restrict__ W2t,
                         short* __restrict__ lw1t, short* __restrict__ lw2t,
                         float* __restrict__ b1f, float* __restrict__ b2f,
                         float* __restrict__ lb1f, float* __restrict__ lb2f,
                         const int* __restrict__ flag)
{
    if (*flag != MODE) return;
    int i = blockIdx.x * 256 + threadIdx.x;
    if (i < 65536) {            // W1t [512][128] <- W1 [128,512]
        int n = i >> 7, k = i & 127;
        W1t[i] = f2bs(ldf(W1, (size_t)k * HID + n));
        return;
    }
    i -= 65536;
    if (i < 262144) {           // W2t [512][512] <- W2 [512,512]
        int n = i >> 9, k = i & 511;
        W2t[i] = f2bs(ldf(W2, (size_t)k * HID + n));
        return;
    }
    i -= 262144;
    if (i < 393216) {           // lw1t [512][768] <- lw1 [712,500], zero-pad
        int n = i / XIN_PAD, k = i - n * XIN_PAD;
        lw1t[i] = (n < MLP1_OUT && k < XIN_DIM)
                      ? f2bs(ldf(lw1, (size_t)k * MLP1_OUT + n)) : (short)0;
        return;
    }
    i -= 393216;
    if (i < 65536) {            // lw2t [128][512] <- lw2 [500,100], zero-pad
        int n = i >> 9, k = i & 511;
        lw2t[i] = (n < MLP2_OUT && k < MLP1_OUT)
                      ? f2bs(ldf(lw2, (size_t)k * MLP2_OUT + n)) : (short)0;
        return;
    }
    i -= 65536;
    if (i < 512) { b1f[i] = ldf(b1, i); return; }
    i -= 512;
    if (i < 512) { b2f[i] = ldf(b2, i); return; }
    i -= 512;
    if (i < 512) { lb1f[i] = (i < MLP1_OUT) ? ldf(lb1, i) : 0.f; return; }
    i -= 512;
    if (i < 128) { lb2f[i] = (i < MLP2_OUT) ? ldf(lb2, i) : 0.f; return; }
}

// ---------------------------------------------------------------------------
// CSR build: deg histogram -> two-level exclusive scan -> fill
// ---------------------------------------------------------------------------
__global__ __launch_bounds__(256)
void deg_kernel(const int* __restrict__ dst, int* __restrict__ deg)
{
    int e = blockIdx.x * 256 + threadIdx.x;
    if (e < N_EDGES) atomicAdd(&deg[dst[e]], 1);
}

__global__ __launch_bounds__(256)
void scan_partial_kernel(const int* __restrict__ deg, int* __restrict__ part)
{
    int c = blockIdx.x, t = threadIdx.x;
    int i0 = c * SCAN_CHUNK + t * 4;
    int s = 0;
#pragma unroll
    for (int j = 0; j < 4; j++) {
        int i = i0 + j;
        if (i < N_NODES) s += deg[i];
    }
    __shared__ int red[256];
    red[t] = s;
    __syncthreads();
    for (int off = 128; off > 0; off >>= 1) {
        if (t < off) red[t] += red[t + off];
        __syncthreads();
    }
    if (t == 0) part[c] = red[0];
}

__global__ void scan_parts_kernel(int* __restrict__ part, int* __restrict__ edge_start)
{
    int run = 0;
    for (int c = 0; c < NCHK; c++) { int v = part[c]; part[c] = run; run += v; }
    edge_start[N_NODES] = run;
}

__global__ __launch_bounds__(256)
void scan_final_kernel(const int* __restrict__ deg, const int* __restrict__ part,
                       int* __restrict__ edge_start)
{
    int c = blockIdx.x, t = threadIdx.x;
    int i0 = c * SCAN_CHUNK + t * 4;
    int d[4];
    int tsum = 0;
#pragma unroll
    for (int j = 0; j < 4; j++) {
        int i = i0 + j;
        d[j] = (i < N_NODES) ? deg[i] : 0;
        tsum += d[j];
    }
    __shared__ int s[256];
    s[t] = tsum;
    __syncthreads();
    for (int off = 1; off < 256; off <<= 1) {
        int v = (t >= off) ? s[t - off] : 0;
        __syncthreads();
        s[t] += v;
        __syncthreads();
    }
    int run = part[c] + s[t] - tsum;
#pragma unroll
    for (int j = 0; j < 4; j++) {
        int i = i0 + j;
        if (i < N_NODES) { edge_start[i] = run; run += d[j]; }
    }
}

__global__ __launch_bounds__(256)
void cursor_kernel(const int* __restrict__ edge_start, int* __restrict__ cursor)
{
    int n = blockIdx.x * 256 + threadIdx.x;
    if (n < N_NODES) cursor[n] = edge_start[n];
}

__global__ __launch_bounds__(256)
void fill_kernel(const int* __restrict__ src, const int* __restrict__ dst,
                 int* __restrict__ cursor, int* __restrict__ csr_src)
{
    int e = blockIdx.x * 256 + threadIdx.x;
    if (e >= N_EDGES) return;
    int p = atomicAdd(&cursor[dst[e]], 1);
    csr_src[p] = src[e];
}

// gstart[g] = first node index with node2graph >= g (node2graph sorted)
__global__ __launch_bounds__(256)
void gstart_kernel(const int* __restrict__ n2g, int* __restrict__ gstart)
{
    int n = blockIdx.x * 256 + threadIdx.x;
    if (n > N_NODES) return;
    if (n == N_NODES) {
        int last = n2g[N_NODES - 1];
        for (int g = last + 1; g <= N_GRAPHS; g++) gstart[g] = N_NODES;
        return;
    }
    int v = n2g[n];
    int prev = (n == 0) ? -1 : n2g[n - 1];
    for (int g = prev + 1; g <= v; g++) gstart[g] = n;
}

// ---------------------------------------------------------------------------
// Layer-1 gather: agg1[n,0:128] = sum_{e: dst=n} feat[src[e],0:128]  (bf16 out)
// ---------------------------------------------------------------------------
template<typename FT, int MODE>
__global__ __launch_bounds__(256)
void gather_feat_kernel(const FT* __restrict__ feat, const int* __restrict__ edge_start,
                        const int* __restrict__ csr_src, bf16* __restrict__ agg1,
                        const int* __restrict__ flag)
{
    if (*flag != MODE) return;
    int n = blockIdx.x * 4 + (threadIdx.x >> 6);
    if (n >= N_NODES) return;
    int lane = threadIdx.x & 63;
    int e0 = edge_start[n], e1 = edge_start[n + 1];
    float2 acc = {0.f, 0.f};
    for (int i = e0; i < e1; i++) {
        int s = csr_src[i];
        float2 f = ld2(feat + (size_t)s * IN_DIM, lane);
        acc.x += f.x; acc.y += f.y;
    }
    bf16x2 p;
    p.x = __float2bfloat16(acc.x);
    p.y = __float2bfloat16(acc.y);
    ((bf16x2*)(agg1 + (size_t)n * IN_DIM))[lane] = p;
}

// ---------------------------------------------------------------------------
// Layer-2 gather: aggc[n,0:512] = sum h1[src,0:512]  (bf16 out, fp32 reg acc)
// ---------------------------------------------------------------------------
__global__ __launch_bounds__(256)
void gather_h_kernel(const bf16* __restrict__ h1, const int* __restrict__ edge_start,
                     const int* __restrict__ csr_src, bf16* __restrict__ aggc)
{
    int n = blockIdx.x * 4 + (threadIdx.x >> 6);
    if (n >= N_NODES) return;
    int lane = threadIdx.x & 63;
    int e0 = edge_start[n], e1 = edge_start[n + 1];
    float acc[8];
#pragma unroll
    for (int j = 0; j < 8; j++) acc[j] = 0.f;
    for (int i = e0; i < e1; i++) {
        int s = csr_src[i];
        float4 r = ((const float4*)(h1 + (size_t)s * HID))[lane];
        const bf16x2* p = (const bf16x2*)&r;
#pragma unroll
        for (int q = 0; q < 4; q++) {
            float2 f = __bfloat1622float2(p[q]);
            acc[2 * q] += f.x; acc[2 * q + 1] += f.y;
        }
    }
    s8v s;
#pragma unroll
    for (int j = 0; j < 8; j++) s[j] = f2bs(acc[j]);
    ((float4*)(aggc + (size_t)n * HID))[lane] = __builtin_bit_cast(float4, s);
}

// ---------------------------------------------------------------------------
// MFMA bf16 GEMM (m97-style + XOR-swizzled LDS): C = relu(A @ Bt^T + b)
// 128x128 tile, BK=64, 256 thr (4 waves, 2x2 of 64x64), 16x16x32 MFMA,
// global_load_lds(16B) staging into unpadded LDS [128][64].
// Swizzle: LDS(row r, stored chunk p) holds global 16B-chunk p^(r&7); the
// staging lane->global-column permutation keeps 128B/8-lane coalescing, and
// fragment reads at chunk g^(r&7) make each 8-lane ds_read phase span all
// 32 banks (kills the 8-way same-bank-group conflicts of the flat layout).
// Grid: blockIdx.x = ROW tile (fast-varying -> A streamed once per col pass),
//       blockIdx.y = COL tile.
// Frag layouts per guide §3 (m89/m91): A:[m=lane&15][k=(lane>>4)*8+j],
// C/D: col=lane&15, row=(lane>>4)*4+reg.
// ---------------------------------------------------------------------------
__global__ __launch_bounds__(256)
void mfma_gemm_kernel(const short* __restrict__ A, const short* __restrict__ Bt,
                      const float* __restrict__ biasf, bf16* __restrict__ Cout,
                      int M, int K)
{
    __shared__ short As[128 * 64];   // 16 KB
    __shared__ short Bs[128 * 64];   // 16 KB

    const int tid  = threadIdx.x;
    const int lane = tid & 63;
    const int w    = tid >> 6;
    const int wr = w >> 1, wc = w & 1;
    const int m  = lane & 15, q = lane >> 4;
    const int row0 = blockIdx.x * 128;   // row tile = fast-varying
    const int col0 = blockIdx.y * 128;

    // Staging: 4 A-chunks + 4 B-chunks per wave (1 KB each). Chunk c covers
    // rows (w*4+c)*8..+7. Lane l -> row +(l>>3), global col ((l&7)^(l>>3))*8.
    const int dr = lane >> 3;
    const int dc = ((lane & 7) ^ dr) * 8;   // XOR swizzle (coalescing preserved)
    const short* ga[4];
    const short* gb[4];
    short* la[4];
    short* lb[4];
#pragma unroll
    for (int c = 0; c < 4; c++) {
        int r = (w * 4 + c) * 8 + dr;
        ga[c] = A  + (size_t)(row0 + r) * K + dc;   // OOB rows: harmless in-ws garbage
        gb[c] = Bt + (size_t)(col0 + r) * K + dc;   // Bt always padded to grid cols
        la[c] = As + (w * 4 + c) * 512;
        lb[c] = Bs + (w * 4 + c) * 512;
    }

    // Fragment-read swizzled chunk offset (shorts): kq=0 -> sa, kq=1 -> sa^32
    const int sa = ((q ^ (m & 7)) * 8);

    f32x4 acc[4][4];
#pragma unroll
    for (int i = 0; i < 4; i++)
#pragma unroll
        for (int j = 0; j < 4; j++) acc[i][j] = {0.f, 0.f, 0.f, 0.f};

    for (int k0 = 0; k0 < K; k0 += 64) {
#pragma unroll
        for (int c = 0; c < 4; c++) gld16(ga[c], la[c]);
#pragma unroll
        for (int c = 0; c < 4; c++) gld16(gb[c], lb[c]);
#pragma unroll
        for (int c = 0; c < 4; c++) { ga[c] += 64; gb[c] += 64; }
        __syncthreads();   // compiler emits s_waitcnt vmcnt(0) before barrier

#pragma unroll
        for (int kq = 0; kq < 2; kq++) {
            const int so = sa ^ (kq * 32);
            s8v av[4], bv[4];
#pragma unroll
            for (int rt = 0; rt < 4; rt++)
                av[rt] = *(const s8v*)&As[(wr * 64 + rt * 16 + m) * 64 + so];
#pragma unroll
            for (int ct = 0; ct < 4; ct++)
                bv[ct] = *(const s8v*)&Bs[(wc * 64 + ct * 16 + m) * 64 + so];
#pragma unroll
            for (int rt = 0; rt < 4; rt++)
#pragma unroll
                for (int ct = 0; ct < 4; ct++)
                    acc[rt][ct] = __builtin_amdgcn_mfma_f32_16x16x32_bf16(
                        av[rt], bv[ct], acc[rt][ct], 0, 0, 0);
        }
        __syncthreads();
    }

    // Epilogue: bias + relu, plain bf16 store (stride 512)
#pragma unroll
    for (int rt = 0; rt < 4; rt++) {
        int rbase = row0 + wr * 64 + rt * 16 + q * 4;
#pragma unroll
        for (int ct = 0; ct < 4; ct++) {
            int col = col0 + wc * 64 + ct * 16 + m;
            float bv = biasf[col];
#pragma unroll
            for (int reg = 0; reg < 4; reg++) {
                int row = rbase + reg;
                if (row < M) {
                    float v = acc[rt][ct][reg] + bv;
                    v = v > 0.f ? v : 0.f;
                    Cout[(size_t)row * HID + col] = __float2bfloat16(v);
                }
            }
        }
    }
}

// ---------------------------------------------------------------------------
// Graph mean-pool numerator, NO atomics: wave per graph (nodes contiguous).
// hg[g, :] = sum_{n in [gstart[g], gstart[g+1])} h2[n, :]
// ---------------------------------------------------------------------------
__global__ __launch_bounds__(256)
void pool_graph_kernel(const bf16* __restrict__ h2, const int* __restrict__ gstart,
                       float* __restrict__ hg)
{
    int g = blockIdx.x * 4 + (threadIdx.x >> 6);
    if (g >= N_GRAPHS) return;
    int lane = threadIdx.x & 63;
    int s0 = gstart[g], s1 = gstart[g + 1];
    float acc[8];
#pragma unroll
    for (int j = 0; j < 8; j++) acc[j] = 0.f;
    for (int n = s0; n < s1; n++) {
        float4 r = ((const float4*)(h2 + (size_t)n * HID))[lane];
        const bf16x2* p = (const bf16x2*)&r;
#pragma unroll
        for (int q = 0; q < 4; q++) {
            float2 f = __bfloat1622float2(p[q]);
            acc[2 * q] += f.x; acc[2 * q + 1] += f.y;
        }
    }
    float* orow = hg + (size_t)g * HID + lane * 8;
    ((float4*)orow)[0] = make_float4(acc[0], acc[1], acc[2], acc[3]);
    ((float4*)orow)[1] = make_float4(acc[4], acc[5], acc[6], acc[7]);
}

// xinb[g, c] (bf16, stride 768) = c<512: hg/cnt | c<712: desc | else 0
template<typename FT, int MODE>
__global__ __launch_bounds__(256)
void build_xin_kernel(const float* __restrict__ hg, const int* __restrict__ gstart,
                      const FT* __restrict__ desc, bf16* __restrict__ xinb,
                      const int* __restrict__ flag)
{
    if (*flag != MODE) return;
    int idx = blockIdx.x * 256 + threadIdx.x;
    if (idx >= N_GRAPHS * XIN_PAD) return;
    int g = idx / XIN_PAD;
    int c = idx - g * XIN_PAD;
    float v;
    if (c < HID) {
        float cnt = (float)(gstart[g + 1] - gstart[g]);
        v = hg[(size_t)g * HID + c] / (cnt > 1.0f ? cnt : 1.0f);
    } else if (c < XIN_DIM) {
        v = ldf(desc, (size_t)g * N_DESC + (c - HID));
    } else {
        v = 0.f;
    }
    xinb[idx] = __float2bfloat16(v);
}

// out[g, c] = x2b[g,:100] @ cw[:,c] + cb[c]; output dtype = FT
template<typename FT, int MODE>
__global__ __launch_bounds__(256)
void final_layer_kernel(const bf16* __restrict__ x2b, const FT* __restrict__ cw,
                        const FT* __restrict__ cb, FT* __restrict__ out,
                        const int* __restrict__ flag)
{
    if (*flag != MODE) return;
    int i = blockIdx.x * 256 + threadIdx.x;
    if (i >= N_GRAPHS * N_CLASSES) return;
    int r = i >> 1, c = i & 1;
    float acc = ldf(cb, c);
    const bf16* x = x2b + (size_t)r * HID;   // stride 512, cols 0..99 valid
#pragma unroll 4
    for (int k = 0; k < MLP2_OUT; k++)
        acc += __bfloat162float(x[k]) * ldf(cw, k * N_CLASSES + c);
    store_out(&out[i], acc);
}

// ---------------------------------------------------------------------------
static inline size_t align_up(size_t x, size_t a) { return (x + a - 1) & ~(a - 1); }

extern "C" void kernel_launch(void* const* d_in, const int* in_sizes, int n_in,
                              void* d_out, int out_size, void* d_ws, size_t ws_size,
                              hipStream_t stream)
{
    const void* features    = d_in[0];
    const void* descriptors = d_in[1];
    const int*  src         = (const int*)d_in[2];
    const int*  dst         = (const int*)d_in[3];
    const int*  node2graph  = (const int*)d_in[4];
    const void* W1          = d_in[5];
    const void* b1          = d_in[6];
    const void* W2          = d_in[7];
    const void* b2          = d_in[8];
    const void* lw1         = d_in[9];
    const void* lb1         = d_in[10];
    const void* lw2         = d_in[11];
    const void* lb2         = d_in[12];
    const void* cw          = d_in[13];
    const void* cb          = d_in[14];
    (void)in_sizes; (void)n_in; (void)out_size; (void)ws_size;

    // ---- Workspace layout (fixed ~218 MB; proven ws >= ~239 MB) ----
    // R_A (102.4 MB): agg1 bf16 [100000,128] -> aggc bf16 [100000,512]
    //                 -> head buffers (xinb @0, x1b @8MB, x2b @16MB)
    // R_B (102.4 MB): h1 bf16 [100000,512] -> h2 bf16 [100000,512]
    char* ws = (char*)d_ws;
    size_t off = 0;
    bf16* agg1 = (bf16*)(ws + off);
    bf16* aggc = (bf16*)(ws + off);
    bf16* xinb = (bf16*)(ws + off);
    bf16* x1b  = (bf16*)(ws + off + (size_t)8 * 1024 * 1024);
    bf16* x2b  = (bf16*)(ws + off + (size_t)16 * 1024 * 1024);
    off = align_up(off + (size_t)N_NODES * HID * sizeof(bf16), 256);   // 102.4 MB
    bf16* h1 = (bf16*)(ws + off);
    bf16* h2 = (bf16*)(ws + off);   // h1 dead after gather_h -> reuse for h2
    off = align_up(off + (size_t)N_NODES * HID * sizeof(bf16), 256);   // +102.4 MB
    float* hg = (float*)(ws + off);
    off = align_up(off + (size_t)N_GRAPHS * HID * sizeof(float), 256); // +8.19 MB
    int* dflag = (int*)(ws + off);          off = align_up(off + 256, 256);
    int* edge_start = (int*)(ws + off);     off = align_up(off + (N_NODES + 1) * 4, 256);
    int* cursor = (int*)(ws + off);         off = align_up(off + N_NODES * 4, 256);
    int* csr_src = (int*)(ws + off);        off = align_up(off + N_EDGES * 4, 256);
    int* part = (int*)(ws + off);           off = align_up(off + NCHK * 4, 256);
    int* deg = (int*)(ws + off);            off = align_up(off + N_NODES * 4, 256);
    int* gstart = (int*)(ws + off);         off = align_up(off + (N_GRAPHS + 1) * 4, 256);
    short* W1t  = (short*)(ws + off);       off = align_up(off + (size_t)HID * IN_DIM * 2, 256);
    short* W2t  = (short*)(ws + off);       off = align_up(off + (size_t)HID * HID * 2, 256);
    short* lw1t = (short*)(ws + off);       off = align_up(off + (size_t)512 * XIN_PAD * 2, 256);
    short* lw2t = (short*)(ws + off);       off = align_up(off + (size_t)128 * HID * 2, 256);
    float* b1f  = (float*)(ws + off);       off = align_up(off + 512 * 4, 256);
    float* b2f  = (float*)(ws + off);       off = align_up(off + 512 * 4, 256);
    float* lb1f = (float*)(ws + off);       off = align_up(off + 512 * 4, 256);
    float* lb2f = (float*)(ws + off);       off = align_up(off + 128 * 4, 256);

    // ---- Detect float-tensor dtype (flag: 0=fp32, 1=bf16) ----
    detect_dtype_kernel<<<1, 256, 0, stream>>>(
        (const unsigned*)features, (unsigned)(N_NODES * IN_DIM / 2), dflag);

    // ---- Weight prep (one fused launch per mode) ----
    {
        int nblk = (788096 + 255) / 256;
        prep_weights_kernel<float, 0><<<nblk, 256, 0, stream>>>(
            (const float*)W1, (const float*)W2, (const float*)lw1, (const float*)lw2,
            (const float*)b1, (const float*)b2, (const float*)lb1, (const float*)lb2,
            W1t, W2t, lw1t, lw2t, b1f, b2f, lb1f, lb2f, dflag);
        prep_weights_kernel<bf16, 1><<<nblk, 256, 0, stream>>>(
            (const bf16*)W1, (const bf16*)W2, (const bf16*)lw1, (const bf16*)lw2,
            (const bf16*)b1, (const bf16*)b2, (const bf16*)lb1, (const bf16*)lb2,
            W1t, W2t, lw1t, lw2t, b1f, b2f, lb1f, lb2f, dflag);
    }

    // ---- CSR build (counting sort by dst) + graph ranges ----
    hipMemsetAsync(deg, 0, N_NODES * 4, stream);
    deg_kernel<<<(N_EDGES + 255) / 256, 256, 0, stream>>>(dst, deg);
    scan_partial_kernel<<<NCHK, 256, 0, stream>>>(deg, part);
    scan_parts_kernel<<<1, 1, 0, stream>>>(part, edge_start);
    scan_final_kernel<<<NCHK, 256, 0, stream>>>(deg, part, edge_start);
    cursor_kernel<<<(N_NODES + 255) / 256, 256, 0, stream>>>(edge_start, cursor);
    fill_kernel<<<(N_EDGES + 255) / 256, 256, 0, stream>>>(src, dst, cursor, csr_src);
    gstart_kernel<<<(N_NODES + 256) / 256, 256, 0, stream>>>(node2graph, gstart);

    // ---- Layer 1: gather -> agg1 (bf16), MFMA GEMM -> h1 (bf16) ----
    gather_feat_kernel<float, 0><<<N_NODES / 4, 256, 0, stream>>>(
        (const float*)features, edge_start, csr_src, agg1, dflag);
    gather_feat_kernel<bf16, 1><<<N_NODES / 4, 256, 0, stream>>>(
        (const bf16*)features, edge_start, csr_src, agg1, dflag);
    {
        dim3 grid((N_NODES + 127) / 128, HID / 128);   // x = row tiles
        mfma_gemm_kernel<<<grid, 256, 0, stream>>>(
            (const short*)agg1, W1t, b1f, h1, N_NODES, IN_DIM);
    }

    // ---- Layer 2: gather h1 -> aggc (bf16), MFMA GEMM -> h2, pool (no atomics)
    gather_h_kernel<<<N_NODES / 4, 256, 0, stream>>>(h1, edge_start, csr_src, aggc);
    {
        dim3 grid((N_NODES + 127) / 128, HID / 128);
        mfma_gemm_kernel<<<grid, 256, 0, stream>>>(
            (const short*)aggc, W2t, b2f, h2, N_NODES, HID);
    }
    pool_graph_kernel<<<N_GRAPHS / 4, 256, 0, stream>>>(h2, gstart, hg);

    // ---- Head (all MFMA; padded-K chaining) ----
    {
        int nthr = (N_GRAPHS * XIN_PAD + 255) / 256;
        build_xin_kernel<float, 0><<<nthr, 256, 0, stream>>>(
            hg, gstart, (const float*)descriptors, xinb, dflag);
        build_xin_kernel<bf16, 1><<<nthr, 256, 0, stream>>>(
            hg, gstart, (const bf16*)descriptors, xinb, dflag);
    }
    {   // x1b[4000,512] = relu(xinb[4000,768] @ lw1t^T + lb1f)
        dim3 grid((N_GRAPHS + 127) / 128, 4);
        mfma_gemm_kernel<<<grid, 256, 0, stream>>>(
            (const short*)xinb, lw1t, lb1f, x1b, N_GRAPHS, XIN_PAD);
    }
    {   // x2b cols 0..127 (stride 512) = relu(x1b @ lw2t^T + lb2f)
        dim3 grid((N_GRAPHS + 127) / 128, 1);
        mfma_gemm_kernel<<<grid, 256, 0, stream>>>(
            (const short*)x1b, lw2t, lb2f, x2b, N_GRAPHS, HID);
    }
    {
        int nthr = (N_GRAPHS * N_CLASSES + 255) / 256;
        final_layer_kernel<float, 0><<<nthr, 256, 0, stream>>>(
            x2b, (const float*)cw, (const float*)cb, (float*)d_out, dflag);
        final_layer_kernel<bf16, 1><<<nthr, 256, 0, stream>>>(
            x2b, (const bf16*)cw, (const bf16*)cb, (bf16*)d_out, dflag);
    }
}

// Round 11
// 511.905 us; speedup vs baseline: 14.5408x; 1.0740x over previous
//
#include <hip/hip_runtime.h>
#include <hip/hip_bf16.h>

// Problem constants (from reference)
#define N_NODES  100000
#define N_EDGES  400000
#define N_GRAPHS 4000
#define IN_DIM   128
#define HID      512
#define N_DESC   200
#define N_CLASSES 2
#define MLP1_OUT 500
#define MLP2_OUT 100
#define XIN_DIM  (HID + N_DESC)   // 712
#define XIN_PAD  768              // K padded to multiple of 64

#define SCAN_CHUNK 1024
#define NCHK ((N_NODES + SCAN_CHUNK - 1) / SCAN_CHUNK)   // 98

typedef __hip_bfloat16  bf16;
typedef __hip_bfloat162 bf16x2;
typedef short s8v  __attribute__((ext_vector_type(8)));   // 8 bf16 (4 VGPRs)
typedef float f32x4 __attribute__((ext_vector_type(4)));

// ---------------------------------------------------------------------------
// Dtype-generic helpers (FT = float or bf16), all produce fp32.
// ---------------------------------------------------------------------------
__device__ __forceinline__ float ldf(const float* p, size_t i) { return p[i]; }
__device__ __forceinline__ float ldf(const bf16* p, size_t i)  { return __bfloat162float(p[i]); }

__device__ __forceinline__ float2 ld2(const float* p, int i) { return ((const float2*)p)[i]; }
__device__ __forceinline__ float2 ld2(const bf16* p, int i)  {
    return __bfloat1622float2(((const bf16x2*)p)[i]);
}

__device__ __forceinline__ void store_out(float* p, float v) { *p = v; }
__device__ __forceinline__ void store_out(bf16* p, float v)  { *p = __float2bfloat16(v); }

__device__ __forceinline__ short f2bs(float x) {
    bf16 h = __float2bfloat16(x);
    return __builtin_bit_cast(short, h);
}

// async global->LDS, 16B per lane; LDS dest = wave-uniform base + lane*16
__device__ __forceinline__ void gld16(const short* g, short* l) {
    __builtin_amdgcn_global_load_lds(
        (const __attribute__((address_space(1))) unsigned int*)g,
        (__attribute__((address_space(3))) unsigned int*)l, 16, 0, 0);
}

// ---------------------------------------------------------------------------
// Runtime dtype detection (flag: 0=fp32, 1=bf16); see round-5 notes.
// ---------------------------------------------------------------------------
__global__ __launch_bounds__(256)
void detect_dtype_kernel(const unsigned* __restrict__ words, unsigned nw,
                         int* __restrict__ flag)
{
    __shared__ int s_cnt;
    if (threadIdx.x == 0) s_cnt = 0;
    __syncthreads();
    const int SAMPLES = 2048;
    int sane = 0;
    for (int i = threadIdx.x; i < SAMPLES; i += 256) {
        size_t idx = (size_t)(((unsigned long long)i * 2654435761ull) % nw);
        unsigned w = words[idx];
        float f = __uint_as_float((w & 0xFFFFu) << 16);
        float a = fabsf(f);
        if (f == 0.0f || (a > 1e-8f && a < 1e8f)) sane++;
    }
    atomicAdd(&s_cnt, sane);
    __syncthreads();
    if (threadIdx.x == 0) *flag = (s_cnt * 10 > SAMPLES * 6) ? 1 : 0;
}

// ---------------------------------------------------------------------------
// Fused weight prep (dual-mode): weights -> transposed bf16 [N][K] (zero-pad),
// biases -> fp32 (zero-pad). Segments: W1t 65536 | W2t 262144 | lw1t 393216 |
// lw2t 65536 | b1f 512 | b2f 512 | lb1f 512 | lb2f 128  (total 788096)
// ---------------------------------------------------------------------------
template<typename FT, int MODE>
__global__ __launch_bounds__(256)
void prep_weights_kernel(const FT* __restrict__ W1, const FT* __restrict__ W2,
                         const FT* __restrict__ lw1, const FT* __restrict__ lw2,
                         const FT* __restrict__ b1, const FT* __restrict__ b2,
                         const FT* __restrict__ lb1, const FT* __restrict__ lb2,
                         short* __restrict__ W1t, short* __restrict__ W2t,
                         short* __restrict__ lw1t, short* __restrict__ lw2t,
                         float* __restrict__ b1f, float* __restrict__ b2f,
                         float* __restrict__ lb1f, float* __restrict__ lb2f,
                         const int* __restrict__ flag)
{
    if (*flag != MODE) return;
    int i = blockIdx.x * 256 + threadIdx.x;
    if (i < 65536) {            // W1t [512][128] <- W1 [128,512]
        int n = i >> 7, k = i & 127;
        W1t[i] = f2bs(ldf(W1, (size_t)k * HID + n));
        return;
    }
    i -= 65536;
    if (i < 262144) {           // W2t [512][512] <- W2 [512,512]
        int n = i >> 9, k = i & 511;
        W2t[i] = f2bs(ldf(W2, (size_t)k * HID + n));
        return;
    }
    i -= 262144;
    if (i < 393216) {           // lw1t [512][768] <- lw1 [712,500], zero-pad
        int n = i / XIN_PAD, k = i - n * XIN_PAD;
        lw1t[i] = (n < MLP1_OUT && k < XIN_DIM)
                      ? f2bs(ldf(lw1, (size_t)k * MLP1_OUT + n)) : (short)0;
        return;
    }
    i -= 393216;
    if (i < 65536) {            // lw2t [128][512] <- lw2 [500,100], zero-pad
        int n = i >> 9, k = i & 511;
        lw2t[i] = (n < MLP2_OUT && k < MLP1_OUT)
                      ? f2bs(ldf(lw2, (size_t)k * MLP2_OUT + n)) : (short)0;
        return;
    }
    i -= 65536;
    if (i < 512) { b1f[i] = ldf(b1, i); return; }
    i -= 512;
    if (i < 512) { b2f[i] = ldf(b2, i); return; }
    i -= 512;
    if (i < 512) { lb1f[i] = (i < MLP1_OUT) ? ldf(lb1, i) : 0.f; return; }
    i -= 512;
    if (i < 128) { lb2f[i] = (i < MLP2_OUT) ? ldf(lb2, i) : 0.f; return; }
}

// ---------------------------------------------------------------------------
// CSR build: deg histogram -> two-level exclusive scan -> fill
// ---------------------------------------------------------------------------
__global__ __launch_bounds__(256)
void deg_kernel(const int* __restrict__ dst, int* __restrict__ deg)
{
    int e = blockIdx.x * 256 + threadIdx.x;
    if (e < N_EDGES) atomicAdd(&deg[dst[e]], 1);
}

__global__ __launch_bounds__(256)
void scan_partial_kernel(const int* __restrict__ deg, int* __restrict__ part)
{
    int c = blockIdx.x, t = threadIdx.x;
    int i0 = c * SCAN_CHUNK + t * 4;
    int s = 0;
#pragma unroll
    for (int j = 0; j < 4; j++) {
        int i = i0 + j;
        if (i < N_NODES) s += deg[i];
    }
    __shared__ int red[256];
    red[t] = s;
    __syncthreads();
    for (int off = 128; off > 0; off >>= 1) {
        if (t < off) red[t] += red[t + off];
        __syncthreads();
    }
    if (t == 0) part[c] = red[0];
}

__global__ void scan_parts_kernel(int* __restrict__ part, int* __restrict__ edge_start)
{
    int run = 0;
    for (int c = 0; c < NCHK; c++) { int v = part[c]; part[c] = run; run += v; }
    edge_start[N_NODES] = run;
}

// also initializes cursor[] (saves a dispatch)
__global__ __launch_bounds__(256)
void scan_final_kernel(const int* __restrict__ deg, const int* __restrict__ part,
                       int* __restrict__ edge_start, int* __restrict__ cursor)
{
    int c = blockIdx.x, t = threadIdx.x;
    int i0 = c * SCAN_CHUNK + t * 4;
    int d[4];
    int tsum = 0;
#pragma unroll
    for (int j = 0; j < 4; j++) {
        int i = i0 + j;
        d[j] = (i < N_NODES) ? deg[i] : 0;
        tsum += d[j];
    }
    __shared__ int s[256];
    s[t] = tsum;
    __syncthreads();
    for (int off = 1; off < 256; off <<= 1) {
        int v = (t >= off) ? s[t - off] : 0;
        __syncthreads();
        s[t] += v;
        __syncthreads();
    }
    int run = part[c] + s[t] - tsum;
#pragma unroll
    for (int j = 0; j < 4; j++) {
        int i = i0 + j;
        if (i < N_NODES) { edge_start[i] = run; cursor[i] = run; run += d[j]; }
    }
}

__global__ __launch_bounds__(256)
void fill_kernel(const int* __restrict__ src, const int* __restrict__ dst,
                 int* __restrict__ cursor, int* __restrict__ csr_src)
{
    int e = blockIdx.x * 256 + threadIdx.x;
    if (e >= N_EDGES) return;
    int p = atomicAdd(&cursor[dst[e]], 1);
    csr_src[p] = src[e];
}

// gstart[g] = first node index with node2graph >= g (node2graph sorted)
__global__ __launch_bounds__(256)
void gstart_kernel(const int* __restrict__ n2g, int* __restrict__ gstart)
{
    int n = blockIdx.x * 256 + threadIdx.x;
    if (n > N_NODES) return;
    if (n == N_NODES) {
        int last = n2g[N_NODES - 1];
        for (int g = last + 1; g <= N_GRAPHS; g++) gstart[g] = N_NODES;
        return;
    }
    int v = n2g[n];
    int prev = (n == 0) ? -1 : n2g[n - 1];
    for (int g = prev + 1; g <= v; g++) gstart[g] = n;
}

// ---------------------------------------------------------------------------
// Layer-1 gather: agg1[n,0:128] = sum_{e: dst=n} feat[src[e],0:128]  (bf16 out)
// ---------------------------------------------------------------------------
template<typename FT, int MODE>
__global__ __launch_bounds__(256)
void gather_feat_kernel(const FT* __restrict__ feat, const int* __restrict__ edge_start,
                        const int* __restrict__ csr_src, bf16* __restrict__ agg1,
                        const int* __restrict__ flag)
{
    if (*flag != MODE) return;
    int n = blockIdx.x * 4 + (threadIdx.x >> 6);
    if (n >= N_NODES) return;
    int lane = threadIdx.x & 63;
    int e0 = edge_start[n], e1 = edge_start[n + 1];
    float2 acc = {0.f, 0.f};
    for (int i = e0; i < e1; i++) {
        int s = csr_src[i];
        float2 f = ld2(feat + (size_t)s * IN_DIM, lane);
        acc.x += f.x; acc.y += f.y;
    }
    bf16x2 p;
    p.x = __float2bfloat16(acc.x);
    p.y = __float2bfloat16(acc.y);
    ((bf16x2*)(agg1 + (size_t)n * IN_DIM))[lane] = p;
}

// ---------------------------------------------------------------------------
// Layer-2 gather: aggc[n,0:512] = sum h1[src,0:512]  (bf16 out, fp32 reg acc)
// ---------------------------------------------------------------------------
__global__ __launch_bounds__(256)
void gather_h_kernel(const bf16* __restrict__ h1, const int* __restrict__ edge_start,
                     const int* __restrict__ csr_src, bf16* __restrict__ aggc)
{
    int n = blockIdx.x * 4 + (threadIdx.x >> 6);
    if (n >= N_NODES) return;
    int lane = threadIdx.x & 63;
    int e0 = edge_start[n], e1 = edge_start[n + 1];
    float acc[8];
#pragma unroll
    for (int j = 0; j < 8; j++) acc[j] = 0.f;
    for (int i = e0; i < e1; i++) {
        int s = csr_src[i];
        float4 r = ((const float4*)(h1 + (size_t)s * HID))[lane];
        const bf16x2* p = (const bf16x2*)&r;
#pragma unroll
        for (int q = 0; q < 4; q++) {
            float2 f = __bfloat1622float2(p[q]);
            acc[2 * q] += f.x; acc[2 * q + 1] += f.y;
        }
    }
    s8v s;
#pragma unroll
    for (int j = 0; j < 8; j++) s[j] = f2bs(acc[j]);
    ((float4*)(aggc + (size_t)n * HID))[lane] = __builtin_bit_cast(float4, s);
}

// ---------------------------------------------------------------------------
// MFMA bf16 GEMM (m97-style + XOR-swizzled LDS + LDS-staged epilogue):
// C = relu(A @ Bt^T + b). 128x128 tile, BK=64, 4 waves (2x2 of 64x64),
// 16x16x32 MFMA, global_load_lds(16B) staging, unpadded LDS [128][64].
// Epilogue stages the bf16 C-tile in LDS (row stride 136 shorts; q-groups 16
// banks apart -> worst 2-way aliasing = free), then stores 16B/lane coalesced
// full cache lines -> no L2 write-allocate RFO (round-10 FETCH showed 2x A).
// Frag layouts per guide §3 (m89/m91): A:[m=lane&15][k=(lane>>4)*8+j],
// C/D: col=lane&15, row=(lane>>4)*4+reg.
// ---------------------------------------------------------------------------
__global__ __launch_bounds__(256)
void mfma_gemm_kernel(const short* __restrict__ A, const short* __restrict__ Bt,
                      const float* __restrict__ biasf, bf16* __restrict__ Cout,
                      int M, int K)
{
    // max(As+Bs = 16384, Cs = 128*136 = 17408) shorts
    __shared__ short smem[17408];
    short* As = smem;            // 8192 shorts
    short* Bs = smem + 8192;     // 8192 shorts
    short* Cs = smem;            // epilogue alias (after final barrier)

    const int tid  = threadIdx.x;
    const int lane = tid & 63;
    const int w    = tid >> 6;
    const int wr = w >> 1, wc = w & 1;
    const int m  = lane & 15, q = lane >> 4;
    const int row0 = blockIdx.x * 128;   // row tile = fast-varying
    const int col0 = blockIdx.y * 128;

    // Staging: 4 A-chunks + 4 B-chunks per wave (1 KB each). Chunk c covers
    // rows (w*4+c)*8..+7. Lane l -> row +(l>>3), global col ((l&7)^(l>>3))*8.
    const int dr = lane >> 3;
    const int dc = ((lane & 7) ^ dr) * 8;   // XOR swizzle (coalescing preserved)
    const short* ga[4];
    const short* gb[4];
    short* la[4];
    short* lb[4];
#pragma unroll
    for (int c = 0; c < 4; c++) {
        int r = (w * 4 + c) * 8 + dr;
        ga[c] = A  + (size_t)(row0 + r) * K + dc;   // OOB rows: harmless in-ws garbage
        gb[c] = Bt + (size_t)(col0 + r) * K + dc;   // Bt always padded to grid cols
        la[c] = As + (w * 4 + c) * 512;
        lb[c] = Bs + (w * 4 + c) * 512;
    }

    // Fragment-read swizzled chunk offset (shorts): kq=0 -> sa, kq=1 -> sa^32
    const int sa = ((q ^ (m & 7)) * 8);

    f32x4 acc[4][4];
#pragma unroll
    for (int i = 0; i < 4; i++)
#pragma unroll
        for (int j = 0; j < 4; j++) acc[i][j] = {0.f, 0.f, 0.f, 0.f};

    for (int k0 = 0; k0 < K; k0 += 64) {
#pragma unroll
        for (int c = 0; c < 4; c++) gld16(ga[c], la[c]);
#pragma unroll
        for (int c = 0; c < 4; c++) gld16(gb[c], lb[c]);
#pragma unroll
        for (int c = 0; c < 4; c++) { ga[c] += 64; gb[c] += 64; }
        __syncthreads();   // compiler emits s_waitcnt vmcnt(0) before barrier

#pragma unroll
        for (int kq = 0; kq < 2; kq++) {
            const int so = sa ^ (kq * 32);
            s8v av[4], bv[4];
#pragma unroll
            for (int rt = 0; rt < 4; rt++)
                av[rt] = *(const s8v*)&As[(wr * 64 + rt * 16 + m) * 64 + so];
#pragma unroll
            for (int ct = 0; ct < 4; ct++)
                bv[ct] = *(const s8v*)&Bs[(wc * 64 + ct * 16 + m) * 64 + so];
#pragma unroll
            for (int rt = 0; rt < 4; rt++)
#pragma unroll
                for (int ct = 0; ct < 4; ct++)
                    acc[rt][ct] = __builtin_amdgcn_mfma_f32_16x16x32_bf16(
                        av[rt], bv[ct], acc[rt][ct], 0, 0, 0);
        }
        __syncthreads();   // last-iter barrier also guards the Cs alias below
    }

    // Epilogue phase 1: bias + relu, write bf16 C-tile into LDS
#pragma unroll
    for (int rt = 0; rt < 4; rt++) {
#pragma unroll
        for (int ct = 0; ct < 4; ct++) {
            int lcol = wc * 64 + ct * 16 + m;
            float bv = biasf[col0 + lcol];
#pragma unroll
            for (int reg = 0; reg < 4; reg++) {
                int lrow = wr * 64 + rt * 16 + q * 4 + reg;
                float v = acc[rt][ct][reg] + bv;
                v = v > 0.f ? v : 0.f;
                Cs[lrow * 136 + lcol] = f2bs(v);
            }
        }
    }
    __syncthreads();

    // Epilogue phase 2: coalesced 16B stores (wave = 4 full 256B row segments)
#pragma unroll
    for (int it = 0; it < 8; it++) {
        int idx = it * 256 + tid;
        int r = idx >> 4;
        int c = (idx & 15) * 8;
        int row = row0 + r;
        if (row < M)
            *(float4*)&Cout[(size_t)row * HID + col0 + c] =
                *(const float4*)&Cs[r * 136 + c];
    }
}

// ---------------------------------------------------------------------------
// Graph mean-pool numerator, NO atomics: wave per graph (nodes contiguous).
// hg[g, :] = sum_{n in [gstart[g], gstart[g+1])} h2[n, :]
// ---------------------------------------------------------------------------
__global__ __launch_bounds__(256)
void pool_graph_kernel(const bf16* __restrict__ h2, const int* __restrict__ gstart,
                       float* __restrict__ hg)
{
    int g = blockIdx.x * 4 + (threadIdx.x >> 6);
    if (g >= N_GRAPHS) return;
    int lane = threadIdx.x & 63;
    int s0 = gstart[g], s1 = gstart[g + 1];
    float acc[8];
#pragma unroll
    for (int j = 0; j < 8; j++) acc[j] = 0.f;
    for (int n = s0; n < s1; n++) {
        float4 r = ((const float4*)(h2 + (size_t)n * HID))[lane];
        const bf16x2* p = (const bf16x2*)&r;
#pragma unroll
        for (int q = 0; q < 4; q++) {
            float2 f = __bfloat1622float2(p[q]);
            acc[2 * q] += f.x; acc[2 * q + 1] += f.y;
        }
    }
    float* orow = hg + (size_t)g * HID + lane * 8;
    ((float4*)orow)[0] = make_float4(acc[0], acc[1], acc[2], acc[3]);
    ((float4*)orow)[1] = make_float4(acc[4], acc[5], acc[6], acc[7]);
}

// xinb[g, c] (bf16, stride 768) = c<512: hg/cnt | c<712: desc | else 0
template<typename FT, int MODE>
__global__ __launch_bounds__(256)
void build_xin_kernel(const float* __restrict__ hg, const int* __restrict__ gstart,
                      const FT* __restrict__ desc, bf16* __restrict__ xinb,
                      const int* __restrict__ flag)
{
    if (*flag != MODE) return;
    int idx = blockIdx.x * 256 + threadIdx.x;
    if (idx >= N_GRAPHS * XIN_PAD) return;
    int g = idx / XIN_PAD;
    int c = idx - g * XIN_PAD;
    float v;
    if (c < HID) {
        float cnt = (float)(gstart[g + 1] - gstart[g]);
        v = hg[(size_t)g * HID + c] / (cnt > 1.0f ? cnt : 1.0f);
    } else if (c < XIN_DIM) {
        v = ldf(desc, (size_t)g * N_DESC + (c - HID));
    } else {
        v = 0.f;
    }
    xinb[idx] = __float2bfloat16(v);
}

// out[g, c] = x2b[g,:100] @ cw[:,c] + cb[c]; output dtype = FT
template<typename FT, int MODE>
__global__ __launch_bounds__(256)
void final_layer_kernel(const bf16* __restrict__ x2b, const FT* __restrict__ cw,
                        const FT* __restrict__ cb, FT* __restrict__ out,
                        const int* __restrict__ flag)
{
    if (*flag != MODE) return;
    int i = blockIdx.x * 256 + threadIdx.x;
    if (i >= N_GRAPHS * N_CLASSES) return;
    int r = i >> 1, c = i & 1;
    float acc = ldf(cb, c);
    const bf16* x = x2b + (size_t)r * HID;   // stride 512, cols 0..99 valid
#pragma unroll 4
    for (int k = 0; k < MLP2_OUT; k++)
        acc += __bfloat162float(x[k]) * ldf(cw, k * N_CLASSES + c);
    store_out(&out[i], acc);
}

// ---------------------------------------------------------------------------
static inline size_t align_up(size_t x, size_t a) { return (x + a - 1) & ~(a - 1); }

extern "C" void kernel_launch(void* const* d_in, const int* in_sizes, int n_in,
                              void* d_out, int out_size, void* d_ws, size_t ws_size,
                              hipStream_t stream)
{
    const void* features    = d_in[0];
    const void* descriptors = d_in[1];
    const int*  src         = (const int*)d_in[2];
    const int*  dst         = (const int*)d_in[3];
    const int*  node2graph  = (const int*)d_in[4];
    const void* W1          = d_in[5];
    const void* b1          = d_in[6];
    const void* W2          = d_in[7];
    const void* b2          = d_in[8];
    const void* lw1         = d_in[9];
    const void* lb1         = d_in[10];
    const void* lw2         = d_in[11];
    const void* lb2         = d_in[12];
    const void* cw          = d_in[13];
    const void* cb          = d_in[14];
    (void)in_sizes; (void)n_in; (void)out_size; (void)ws_size;

    // ---- Workspace layout (fixed ~218 MB; proven ws >= ~239 MB) ----
    // R_A (102.4 MB): agg1 bf16 [100000,128] -> aggc bf16 [100000,512]
    //                 -> head buffers (xinb @0, x1b @8MB, x2b @16MB)
    // R_B (102.4 MB): h1 bf16 [100000,512] -> h2 bf16 [100000,512]
    char* ws = (char*)d_ws;
    size_t off = 0;
    bf16* agg1 = (bf16*)(ws + off);
    bf16* aggc = (bf16*)(ws + off);
    bf16* xinb = (bf16*)(ws + off);
    bf16* x1b  = (bf16*)(ws + off + (size_t)8 * 1024 * 1024);
    bf16* x2b  = (bf16*)(ws + off + (size_t)16 * 1024 * 1024);
    off = align_up(off + (size_t)N_NODES * HID * sizeof(bf16), 256);   // 102.4 MB
    bf16* h1 = (bf16*)(ws + off);
    bf16* h2 = (bf16*)(ws + off);   // h1 dead after gather_h -> reuse for h2
    off = align_up(off + (size_t)N_NODES * HID * sizeof(bf16), 256);   // +102.4 MB
    float* hg = (float*)(ws + off);
    off = align_up(off + (size_t)N_GRAPHS * HID * sizeof(float), 256); // +8.19 MB
    int* dflag = (int*)(ws + off);          off = align_up(off + 256, 256);
    int* edge_start = (int*)(ws + off);     off = align_up(off + (N_NODES + 1) * 4, 256);
    int* cursor = (int*)(ws + off);         off = align_up(off + N_NODES * 4, 256);
    int* csr_src = (int*)(ws + off);        off = align_up(off + N_EDGES * 4, 256);
    int* part = (int*)(ws + off);           off = align_up(off + NCHK * 4, 256);
    int* deg = (int*)(ws + off);            off = align_up(off + N_NODES * 4, 256);
    int* gstart = (int*)(ws + off);         off = align_up(off + (N_GRAPHS + 1) * 4, 256);
    short* W1t  = (short*)(ws + off);       off = align_up(off + (size_t)HID * IN_DIM * 2, 256);
    short* W2t  = (short*)(ws + off);       off = align_up(off + (size_t)HID * HID * 2, 256);
    short* lw1t = (short*)(ws + off);       off = align_up(off + (size_t)512 * XIN_PAD * 2, 256);
    short* lw2t = (short*)(ws + off);       off = align_up(off + (size_t)128 * HID * 2, 256);
    float* b1f  = (float*)(ws + off);       off = align_up(off + 512 * 4, 256);
    float* b2f  = (float*)(ws + off);       off = align_up(off + 512 * 4, 256);
    float* lb1f = (float*)(ws + off);       off = align_up(off + 512 * 4, 256);
    float* lb2f = (float*)(ws + off);       off = align_up(off + 128 * 4, 256);

    // ---- Detect float-tensor dtype (flag: 0=fp32, 1=bf16) ----
    detect_dtype_kernel<<<1, 256, 0, stream>>>(
        (const unsigned*)features, (unsigned)(N_NODES * IN_DIM / 2), dflag);

    // ---- Weight prep (one fused launch per mode) ----
    {
        int nblk = (788096 + 255) / 256;
        prep_weights_kernel<float, 0><<<nblk, 256, 0, stream>>>(
            (const float*)W1, (const float*)W2, (const float*)lw1, (const float*)lw2,
            (const float*)b1, (const float*)b2, (const float*)lb1, (const float*)lb2,
            W1t, W2t, lw1t, lw2t, b1f, b2f, lb1f, lb2f, dflag);
        prep_weights_kernel<bf16, 1><<<nblk, 256, 0, stream>>>(
            (const bf16*)W1, (const bf16*)W2, (const bf16*)lw1, (const bf16*)lw2,
            (const bf16*)b1, (const bf16*)b2, (const bf16*)lb1, (const bf16*)lb2,
            W1t, W2t, lw1t, lw2t, b1f, b2f, lb1f, lb2f, dflag);
    }

    // ---- CSR build (counting sort by dst) + graph ranges ----
    hipMemsetAsync(deg, 0, N_NODES * 4, stream);
    deg_kernel<<<(N_EDGES + 255) / 256, 256, 0, stream>>>(dst, deg);
    scan_partial_kernel<<<NCHK, 256, 0, stream>>>(deg, part);
    scan_parts_kernel<<<1, 1, 0, stream>>>(part, edge_start);
    scan_final_kernel<<<NCHK, 256, 0, stream>>>(deg, part, edge_start, cursor);
    fill_kernel<<<(N_EDGES + 255) / 256, 256, 0, stream>>>(src, dst, cursor, csr_src);
    gstart_kernel<<<(N_NODES + 256) / 256, 256, 0, stream>>>(node2graph, gstart);

    // ---- Layer 1: gather -> agg1 (bf16), MFMA GEMM -> h1 (bf16) ----
    gather_feat_kernel<float, 0><<<N_NODES / 4, 256, 0, stream>>>(
        (const float*)features, edge_start, csr_src, agg1, dflag);
    gather_feat_kernel<bf16, 1><<<N_NODES / 4, 256, 0, stream>>>(
        (const bf16*)features, edge_start, csr_src, agg1, dflag);
    {
        dim3 grid((N_NODES + 127) / 128, HID / 128);   // x = row tiles
        mfma_gemm_kernel<<<grid, 256, 0, stream>>>(
            (const short*)agg1, W1t, b1f, h1, N_NODES, IN_DIM);
    }

    // ---- Layer 2: gather h1 -> aggc (bf16), MFMA GEMM -> h2, pool (no atomics)
    gather_h_kernel<<<N_NODES / 4, 256, 0, stream>>>(h1, edge_start, csr_src, aggc);
    {
        dim3 grid((N_NODES + 127) / 128, HID / 128);
        mfma_gemm_kernel<<<grid, 256, 0, stream>>>(
            (const short*)aggc, W2t, b2f, h2, N_NODES, HID);
    }
    pool_graph_kernel<<<N_GRAPHS / 4, 256, 0, stream>>>(h2, gstart, hg);

    // ---- Head (all MFMA; padded-K chaining) ----
    {
        int nthr = (N_GRAPHS * XIN_PAD + 255) / 256;
        build_xin_kernel<float, 0><<<nthr, 256, 0, stream>>>(
            hg, gstart, (const float*)descriptors, xinb, dflag);
        build_xin_kernel<bf16, 1><<<nthr, 256, 0, stream>>>(
            hg, gstart, (const bf16*)descriptors, xinb, dflag);
    }
    {   // x1b[4000,512] = relu(xinb[4000,768] @ lw1t^T + lb1f)
        dim3 grid((N_GRAPHS + 127) / 128, 4);
        mfma_gemm_kernel<<<grid, 256, 0, stream>>>(
            (const short*)xinb, lw1t, lb1f, x1b, N_GRAPHS, XIN_PAD);
    }
    {   // x2b cols 0..127 (stride 512) = relu(x1b @ lw2t^T + lb2f)
        dim3 grid((N_GRAPHS + 127) / 128, 1);
        mfma_gemm_kernel<<<grid, 256, 0, stream>>>(
            (const short*)x1b, lw2t, lb2f, x2b, N_GRAPHS, HID);
    }
    {
        int nthr = (N_GRAPHS * N_CLASSES + 255) / 256;
        final_layer_kernel<float, 0><<<nthr, 256, 0, stream>>>(
            x2b, (const float*)cw, (const float*)cb, (float*)d_out, dflag);
        final_layer_kernel<bf16, 1><<<nthr, 256, 0, stream>>>(
            x2b, (const bf16*)cw, (const bf16*)cb, (bf16*)d_out, dflag);
    }
}

// Round 12
// 478.452 us; speedup vs baseline: 15.5575x; 1.0699x over previous
//
#include <hip/hip_runtime.h>
#include <hip/hip_bf16.h>

// Problem constants (from reference)
#define N_NODES  100000
#define N_EDGES  400000
#define N_GRAPHS 4000
#define IN_DIM   128
#define HID      512
#define N_DESC   200
#define N_CLASSES 2
#define MLP1_OUT 500
#define MLP2_OUT 100
#define XIN_DIM  (HID + N_DESC)   // 712
#define XIN_PAD  768              // K padded to multiple of 64

#define SCAN_CHUNK 1024
#define NCHK ((N_NODES + SCAN_CHUNK - 1) / SCAN_CHUNK)   // 98

typedef __hip_bfloat16  bf16;
typedef __hip_bfloat162 bf16x2;
typedef short s8v  __attribute__((ext_vector_type(8)));   // 8 bf16 (4 VGPRs)
typedef float f32x4 __attribute__((ext_vector_type(4)));

// ---------------------------------------------------------------------------
// Dtype-generic helpers (FT = float or bf16), all produce fp32.
// ---------------------------------------------------------------------------
__device__ __forceinline__ float ldf(const float* p, size_t i) { return p[i]; }
__device__ __forceinline__ float ldf(const bf16* p, size_t i)  { return __bfloat162float(p[i]); }

__device__ __forceinline__ float2 ld2(const float* p, int i) { return ((const float2*)p)[i]; }
__device__ __forceinline__ float2 ld2(const bf16* p, int i)  {
    return __bfloat1622float2(((const bf16x2*)p)[i]);
}

__device__ __forceinline__ void store_out(float* p, float v) { *p = v; }
__device__ __forceinline__ void store_out(bf16* p, float v)  { *p = __float2bfloat16(v); }

__device__ __forceinline__ short f2bs(float x) {
    bf16 h = __float2bfloat16(x);
    return __builtin_bit_cast(short, h);
}

// async global->LDS, 16B per lane; LDS dest = wave-uniform base + lane*16
__device__ __forceinline__ void gld16(const short* g, short* l) {
    __builtin_amdgcn_global_load_lds(
        (const __attribute__((address_space(1))) unsigned int*)g,
        (__attribute__((address_space(3))) unsigned int*)l, 16, 0, 0);
}

// ---------------------------------------------------------------------------
// Runtime dtype detection (flag: 0=fp32, 1=bf16); see round-5 notes.
// ---------------------------------------------------------------------------
__global__ __launch_bounds__(256)
void detect_dtype_kernel(const unsigned* __restrict__ words, unsigned nw,
                         int* __restrict__ flag)
{
    __shared__ int s_cnt;
    if (threadIdx.x == 0) s_cnt = 0;
    __syncthreads();
    const int SAMPLES = 2048;
    int sane = 0;
    for (int i = threadIdx.x; i < SAMPLES; i += 256) {
        size_t idx = (size_t)(((unsigned long long)i * 2654435761ull) % nw);
        unsigned w = words[idx];
        float f = __uint_as_float((w & 0xFFFFu) << 16);
        float a = fabsf(f);
        if (f == 0.0f || (a > 1e-8f && a < 1e8f)) sane++;
    }
    atomicAdd(&s_cnt, sane);
    __syncthreads();
    if (threadIdx.x == 0) *flag = (s_cnt * 10 > SAMPLES * 6) ? 1 : 0;
}

// ---------------------------------------------------------------------------
// Fused weight prep (dual-mode): weights -> transposed bf16 [N][K] (zero-pad),
// biases -> fp32 (zero-pad). Segments: W1t 65536 | W2t 262144 | lw1t 393216 |
// lw2t 65536 | b1f 512 | b2f 512 | lb1f 512 | lb2f 128  (total 788096)
// ---------------------------------------------------------------------------
template<typename FT, int MODE>
__global__ __launch_bounds__(256)
void prep_weights_kernel(const FT* __restrict__ W1, const FT* __restrict__ W2,
                         const FT* __restrict__ lw1, const FT* __restrict__ lw2,
                         const FT* __restrict__ b1, const FT* __restrict__ b2,
                         const FT* __restrict__ lb1, const FT* __restrict__ lb2,
                         short* __restrict__ W1t, short* __restrict__ W2t,
                         short* __restrict__ lw1t, short* __restrict__ lw2t,
                         float* __restrict__ b1f, float* __restrict__ b2f,
                         float* __restrict__ lb1f, float* __restrict__ lb2f,
                         const int* __restrict__ flag)
{
    if (*flag != MODE) return;
    int i = blockIdx.x * 256 + threadIdx.x;
    if (i < 65536) {            // W1t [512][128] <- W1 [128,512]
        int n = i >> 7, k = i & 127;
        W1t[i] = f2bs(ldf(W1, (size_t)k * HID + n));
        return;
    }
    i -= 65536;
    if (i < 262144) {           // W2t [512][512] <- W2 [512,512]
        int n = i >> 9, k = i & 511;
        W2t[i] = f2bs(ldf(W2, (size_t)k * HID + n));
        return;
    }
    i -= 262144;
    if (i < 393216) {           // lw1t [512][768] <- lw1 [712,500], zero-pad
        int n = i / XIN_PAD, k = i - n * XIN_PAD;
        lw1t[i] = (n < MLP1_OUT && k < XIN_DIM)
                      ? f2bs(ldf(lw1, (size_t)k * MLP1_OUT + n)) : (short)0;
        return;
    }
    i -= 393216;
    if (i < 65536) {            // lw2t [128][512] <- lw2 [500,100], zero-pad
        int n = i >> 9, k = i & 511;
        lw2t[i] = (n < MLP2_OUT && k < MLP1_OUT)
                      ? f2bs(ldf(lw2, (size_t)k * MLP2_OUT + n)) : (short)0;
        return;
    }
    i -= 65536;
    if (i < 512) { b1f[i] = ldf(b1, i); return; }
    i -= 512;
    if (i < 512) { b2f[i] = ldf(b2, i); return; }
    i -= 512;
    if (i < 512) { lb1f[i] = (i < MLP1_OUT) ? ldf(lb1, i) : 0.f; return; }
    i -= 512;
    if (i < 128) { lb2f[i] = (i < MLP2_OUT) ? ldf(lb2, i) : 0.f; return; }
}

// ---------------------------------------------------------------------------
// CSR build: deg histogram -> two-level exclusive scan -> fill
// ---------------------------------------------------------------------------
__global__ __launch_bounds__(256)
void deg_kernel(const int* __restrict__ dst, int* __restrict__ deg)
{
    int e = blockIdx.x * 256 + threadIdx.x;
    if (e < N_EDGES) atomicAdd(&deg[dst[e]], 1);
}

__global__ __launch_bounds__(256)
void scan_partial_kernel(const int* __restrict__ deg, int* __restrict__ part)
{
    int c = blockIdx.x, t = threadIdx.x;
    int i0 = c * SCAN_CHUNK + t * 4;
    int s = 0;
#pragma unroll
    for (int j = 0; j < 4; j++) {
        int i = i0 + j;
        if (i < N_NODES) s += deg[i];
    }
    __shared__ int red[256];
    red[t] = s;
    __syncthreads();
    for (int off = 128; off > 0; off >>= 1) {
        if (t < off) red[t] += red[t + off];
        __syncthreads();
    }
    if (t == 0) part[c] = red[0];
}

__global__ void scan_parts_kernel(int* __restrict__ part, int* __restrict__ edge_start)
{
    int run = 0;
    for (int c = 0; c < NCHK; c++) { int v = part[c]; part[c] = run; run += v; }
    edge_start[N_NODES] = run;
}

// also initializes cursor[] (saves a dispatch)
__global__ __launch_bounds__(256)
void scan_final_kernel(const int* __restrict__ deg, const int* __restrict__ part,
                       int* __restrict__ edge_start, int* __restrict__ cursor)
{
    int c = blockIdx.x, t = threadIdx.x;
    int i0 = c * SCAN_CHUNK + t * 4;
    int d[4];
    int tsum = 0;
#pragma unroll
    for (int j = 0; j < 4; j++) {
        int i = i0 + j;
        d[j] = (i < N_NODES) ? deg[i] : 0;
        tsum += d[j];
    }
    __shared__ int s[256];
    s[t] = tsum;
    __syncthreads();
    for (int off = 1; off < 256; off <<= 1) {
        int v = (t >= off) ? s[t - off] : 0;
        __syncthreads();
        s[t] += v;
        __syncthreads();
    }
    int run = part[c] + s[t] - tsum;
#pragma unroll
    for (int j = 0; j < 4; j++) {
        int i = i0 + j;
        if (i < N_NODES) { edge_start[i] = run; cursor[i] = run; run += d[j]; }
    }
}

__global__ __launch_bounds__(256)
void fill_kernel(const int* __restrict__ src, const int* __restrict__ dst,
                 int* __restrict__ cursor, int* __restrict__ csr_src)
{
    int e = blockIdx.x * 256 + threadIdx.x;
    if (e >= N_EDGES) return;
    int p = atomicAdd(&cursor[dst[e]], 1);
    csr_src[p] = src[e];
}

// gstart[g] = first node index with node2graph >= g (node2graph sorted)
__global__ __launch_bounds__(256)
void gstart_kernel(const int* __restrict__ n2g, int* __restrict__ gstart)
{
    int n = blockIdx.x * 256 + threadIdx.x;
    if (n > N_NODES) return;
    if (n == N_NODES) {
        int last = n2g[N_NODES - 1];
        for (int g = last + 1; g <= N_GRAPHS; g++) gstart[g] = N_NODES;
        return;
    }
    int v = n2g[n];
    int prev = (n == 0) ? -1 : n2g[n - 1];
    for (int g = prev + 1; g <= v; g++) gstart[g] = n;
}

// ---------------------------------------------------------------------------
// Layer-1 gather: agg1[n,0:128] = sum_{e: dst=n} feat[src[e],0:128]  (bf16 out)
// ---------------------------------------------------------------------------
template<typename FT, int MODE>
__global__ __launch_bounds__(256)
void gather_feat_kernel(const FT* __restrict__ feat, const int* __restrict__ edge_start,
                        const int* __restrict__ csr_src, bf16* __restrict__ agg1,
                        const int* __restrict__ flag)
{
    if (*flag != MODE) return;
    int n = blockIdx.x * 4 + (threadIdx.x >> 6);
    if (n >= N_NODES) return;
    int lane = threadIdx.x & 63;
    int e0 = edge_start[n], e1 = edge_start[n + 1];
    float2 acc = {0.f, 0.f};
    for (int i = e0; i < e1; i++) {
        int s = csr_src[i];
        float2 f = ld2(feat + (size_t)s * IN_DIM, lane);
        acc.x += f.x; acc.y += f.y;
    }
    bf16x2 p;
    p.x = __float2bfloat16(acc.x);
    p.y = __float2bfloat16(acc.y);
    ((bf16x2*)(agg1 + (size_t)n * IN_DIM))[lane] = p;
}

// ---------------------------------------------------------------------------
// Layer-2 gather: aggc[n,0:512] = sum h1[src,0:512]  (bf16 out, fp32 reg acc)
// ---------------------------------------------------------------------------
__global__ __launch_bounds__(256)
void gather_h_kernel(const bf16* __restrict__ h1, const int* __restrict__ edge_start,
                     const int* __restrict__ csr_src, bf16* __restrict__ aggc)
{
    int n = blockIdx.x * 4 + (threadIdx.x >> 6);
    if (n >= N_NODES) return;
    int lane = threadIdx.x & 63;
    int e0 = edge_start[n], e1 = edge_start[n + 1];
    float acc[8];
#pragma unroll
    for (int j = 0; j < 8; j++) acc[j] = 0.f;
    for (int i = e0; i < e1; i++) {
        int s = csr_src[i];
        float4 r = ((const float4*)(h1 + (size_t)s * HID))[lane];
        const bf16x2* p = (const bf16x2*)&r;
#pragma unroll
        for (int q = 0; q < 4; q++) {
            float2 f = __bfloat1622float2(p[q]);
            acc[2 * q] += f.x; acc[2 * q + 1] += f.y;
        }
    }
    s8v s;
#pragma unroll
    for (int j = 0; j < 8; j++) s[j] = f2bs(acc[j]);
    ((float4*)(aggc + (size_t)n * HID))[lane] = __builtin_bit_cast(float4, s);
}

// ---------------------------------------------------------------------------
// MFMA bf16 GEMM (m97-style + XOR-swizzled LDS + LDS-staged epilogue +
// XCD-colocating block swizzle): C = relu(A @ Bt^T + b).
// 128x128 tile, BK=64, 4 waves (2x2 of 64x64), 16x16x32 MFMA,
// global_load_lds(16B) staging into unpadded LDS [128][64].
// 1D grid, decode: r8=b&7, t=b>>3, y=t%NCT, x=(t/NCT)*8+r8. All NCT col-tiles
// of row-tile x share id residue x%8 -> same XCD (id->XCD = id%8 round-robin)
// and are temporally adjacent -> A row-tile fetched once per XCD L2 (round-11
// FETCH showed 2x A from cross-XCD spreading of col-tiles).
// Frag layouts per guide §3 (m89/m91): A:[m=lane&15][k=(lane>>4)*8+j],
// C/D: col=lane&15, row=(lane>>4)*4+reg.
// ---------------------------------------------------------------------------
template<int NCT>
__global__ __launch_bounds__(256)
void mfma_gemm_kernel(const short* __restrict__ A, const short* __restrict__ Bt,
                      const float* __restrict__ biasf, bf16* __restrict__ Cout,
                      int M, int K, int nrt)
{
    // max(As+Bs = 16384, Cs = 128*136 = 17408) shorts
    __shared__ short smem[17408];
    short* As = smem;            // 8192 shorts
    short* Bs = smem + 8192;     // 8192 shorts
    short* Cs = smem;            // epilogue alias (after final barrier)

    // XCD-colocating decode
    const int b  = blockIdx.x;
    const int r8 = b & 7;
    const int t  = b >> 3;
    const int x  = (t / NCT) * 8 + r8;
    const int y  = t % NCT;
    if (x >= nrt) return;
    const int row0 = x * 128;
    const int col0 = y * 128;

    const int tid  = threadIdx.x;
    const int lane = tid & 63;
    const int w    = tid >> 6;
    const int wr = w >> 1, wc = w & 1;
    const int m  = lane & 15, q = lane >> 4;

    // Staging: 4 A-chunks + 4 B-chunks per wave (1 KB each). Chunk c covers
    // rows (w*4+c)*8..+7. Lane l -> row +(l>>3), global col ((l&7)^(l>>3))*8.
    const int dr = lane >> 3;
    const int dc = ((lane & 7) ^ dr) * 8;   // XOR swizzle (coalescing preserved)
    const short* ga[4];
    const short* gb[4];
    short* la[4];
    short* lb[4];
#pragma unroll
    for (int c = 0; c < 4; c++) {
        int r = (w * 4 + c) * 8 + dr;
        ga[c] = A  + (size_t)(row0 + r) * K + dc;   // OOB rows: harmless in-ws garbage
        gb[c] = Bt + (size_t)(col0 + r) * K + dc;   // Bt always padded to grid cols
        la[c] = As + (w * 4 + c) * 512;
        lb[c] = Bs + (w * 4 + c) * 512;
    }

    // Fragment-read swizzled chunk offset (shorts): kq=0 -> sa, kq=1 -> sa^32
    const int sa = ((q ^ (m & 7)) * 8);

    f32x4 acc[4][4];
#pragma unroll
    for (int i = 0; i < 4; i++)
#pragma unroll
        for (int j = 0; j < 4; j++) acc[i][j] = {0.f, 0.f, 0.f, 0.f};

    for (int k0 = 0; k0 < K; k0 += 64) {
#pragma unroll
        for (int c = 0; c < 4; c++) gld16(ga[c], la[c]);
#pragma unroll
        for (int c = 0; c < 4; c++) gld16(gb[c], lb[c]);
#pragma unroll
        for (int c = 0; c < 4; c++) { ga[c] += 64; gb[c] += 64; }
        __syncthreads();   // compiler emits s_waitcnt vmcnt(0) before barrier

#pragma unroll
        for (int kq = 0; kq < 2; kq++) {
            const int so = sa ^ (kq * 32);
            s8v av[4], bv[4];
#pragma unroll
            for (int rt = 0; rt < 4; rt++)
                av[rt] = *(const s8v*)&As[(wr * 64 + rt * 16 + m) * 64 + so];
#pragma unroll
            for (int ct = 0; ct < 4; ct++)
                bv[ct] = *(const s8v*)&Bs[(wc * 64 + ct * 16 + m) * 64 + so];
#pragma unroll
            for (int rt = 0; rt < 4; rt++)
#pragma unroll
                for (int ct = 0; ct < 4; ct++)
                    acc[rt][ct] = __builtin_amdgcn_mfma_f32_16x16x32_bf16(
                        av[rt], bv[ct], acc[rt][ct], 0, 0, 0);
        }
        __syncthreads();   // last-iter barrier also guards the Cs alias below
    }

    // Epilogue phase 1: bias + relu, write bf16 C-tile into LDS
#pragma unroll
    for (int rt = 0; rt < 4; rt++) {
#pragma unroll
        for (int ct = 0; ct < 4; ct++) {
            int lcol = wc * 64 + ct * 16 + m;
            float bv = biasf[col0 + lcol];
#pragma unroll
            for (int reg = 0; reg < 4; reg++) {
                int lrow = wr * 64 + rt * 16 + q * 4 + reg;
                float v = acc[rt][ct][reg] + bv;
                v = v > 0.f ? v : 0.f;
                Cs[lrow * 136 + lcol] = f2bs(v);
            }
        }
    }
    __syncthreads();

    // Epilogue phase 2: coalesced 16B stores (wave = 4 full 256B row segments)
#pragma unroll
    for (int it = 0; it < 8; it++) {
        int idx = it * 256 + tid;
        int r = idx >> 4;
        int c = (idx & 15) * 8;
        int row = row0 + r;
        if (row < M)
            *(float4*)&Cout[(size_t)row * HID + col0 + c] =
                *(const float4*)&Cs[r * 136 + c];
    }
}

// ---------------------------------------------------------------------------
// Graph mean-pool numerator, NO atomics: wave per graph (nodes contiguous).
// hg[g, :] = sum_{n in [gstart[g], gstart[g+1])} h2[n, :]
// ---------------------------------------------------------------------------
__global__ __launch_bounds__(256)
void pool_graph_kernel(const bf16* __restrict__ h2, const int* __restrict__ gstart,
                       float* __restrict__ hg)
{
    int g = blockIdx.x * 4 + (threadIdx.x >> 6);
    if (g >= N_GRAPHS) return;
    int lane = threadIdx.x & 63;
    int s0 = gstart[g], s1 = gstart[g + 1];
    float acc[8];
#pragma unroll
    for (int j = 0; j < 8; j++) acc[j] = 0.f;
    for (int n = s0; n < s1; n++) {
        float4 r = ((const float4*)(h2 + (size_t)n * HID))[lane];
        const bf16x2* p = (const bf16x2*)&r;
#pragma unroll
        for (int q = 0; q < 4; q++) {
            float2 f = __bfloat1622float2(p[q]);
            acc[2 * q] += f.x; acc[2 * q + 1] += f.y;
        }
    }
    float* orow = hg + (size_t)g * HID + lane * 8;
    ((float4*)orow)[0] = make_float4(acc[0], acc[1], acc[2], acc[3]);
    ((float4*)orow)[1] = make_float4(acc[4], acc[5], acc[6], acc[7]);
}

// xinb[g, c] (bf16, stride 768) = c<512: hg/cnt | c<712: desc | else 0
template<typename FT, int MODE>
__global__ __launch_bounds__(256)
void build_xin_kernel(const float* __restrict__ hg, const int* __restrict__ gstart,
                      const FT* __restrict__ desc, bf16* __restrict__ xinb,
                      const int* __restrict__ flag)
{
    if (*flag != MODE) return;
    int idx = blockIdx.x * 256 + threadIdx.x;
    if (idx >= N_GRAPHS * XIN_PAD) return;
    int g = idx / XIN_PAD;
    int c = idx - g * XIN_PAD;
    float v;
    if (c < HID) {
        float cnt = (float)(gstart[g + 1] - gstart[g]);
        v = hg[(size_t)g * HID + c] / (cnt > 1.0f ? cnt : 1.0f);
    } else if (c < XIN_DIM) {
        v = ldf(desc, (size_t)g * N_DESC + (c - HID));
    } else {
        v = 0.f;
    }
    xinb[idx] = __float2bfloat16(v);
}

// out[g, c] = x2b[g,:100] @ cw[:,c] + cb[c]; output dtype = FT
template<typename FT, int MODE>
__global__ __launch_bounds__(256)
void final_layer_kernel(const bf16* __restrict__ x2b, const FT* __restrict__ cw,
                        const FT* __restrict__ cb, FT* __restrict__ out,
                        const int* __restrict__ flag)
{
    if (*flag != MODE) return;
    int i = blockIdx.x * 256 + threadIdx.x;
    if (i >= N_GRAPHS * N_CLASSES) return;
    int r = i >> 1, c = i & 1;
    float acc = ldf(cb, c);
    const bf16* x = x2b + (size_t)r * HID;   // stride 512, cols 0..99 valid
#pragma unroll 4
    for (int k = 0; k < MLP2_OUT; k++)
        acc += __bfloat162float(x[k]) * ldf(cw, k * N_CLASSES + c);
    store_out(&out[i], acc);
}

// ---------------------------------------------------------------------------
static inline size_t align_up(size_t x, size_t a) { return (x + a - 1) & ~(a - 1); }
static inline int swgrid(int nrt, int nct) { return ((nrt + 7) / 8) * 8 * nct; }

extern "C" void kernel_launch(void* const* d_in, const int* in_sizes, int n_in,
                              void* d_out, int out_size, void* d_ws, size_t ws_size,
                              hipStream_t stream)
{
    const void* features    = d_in[0];
    const void* descriptors = d_in[1];
    const int*  src         = (const int*)d_in[2];
    const int*  dst         = (const int*)d_in[3];
    const int*  node2graph  = (const int*)d_in[4];
    const void* W1          = d_in[5];
    const void* b1          = d_in[6];
    const void* W2          = d_in[7];
    const void* b2          = d_in[8];
    const void* lw1         = d_in[9];
    const void* lb1         = d_in[10];
    const void* lw2         = d_in[11];
    const void* lb2         = d_in[12];
    const void* cw          = d_in[13];
    const void* cb          = d_in[14];
    (void)in_sizes; (void)n_in; (void)out_size; (void)ws_size;

    // ---- Workspace layout (fixed ~218 MB; proven ws >= ~239 MB) ----
    // R_A (102.4 MB): agg1 bf16 [100000,128] -> aggc bf16 [100000,512]
    //                 -> head buffers (xinb @0, x1b @8MB, x2b @16MB)
    // R_B (102.4 MB): h1 bf16 [100000,512] -> h2 bf16 [100000,512]
    char* ws = (char*)d_ws;
    size_t off = 0;
    bf16* agg1 = (bf16*)(ws + off);
    bf16* aggc = (bf16*)(ws + off);
    bf16* xinb = (bf16*)(ws + off);
    bf16* x1b  = (bf16*)(ws + off + (size_t)8 * 1024 * 1024);
    bf16* x2b  = (bf16*)(ws + off + (size_t)16 * 1024 * 1024);
    off = align_up(off + (size_t)N_NODES * HID * sizeof(bf16), 256);   // 102.4 MB
    bf16* h1 = (bf16*)(ws + off);
    bf16* h2 = (bf16*)(ws + off);   // h1 dead after gather_h -> reuse for h2
    off = align_up(off + (size_t)N_NODES * HID * sizeof(bf16), 256);   // +102.4 MB
    float* hg = (float*)(ws + off);
    off = align_up(off + (size_t)N_GRAPHS * HID * sizeof(float), 256); // +8.19 MB
    int* dflag = (int*)(ws + off);          off = align_up(off + 256, 256);
    int* edge_start = (int*)(ws + off);     off = align_up(off + (N_NODES + 1) * 4, 256);
    int* cursor = (int*)(ws + off);         off = align_up(off + N_NODES * 4, 256);
    int* csr_src = (int*)(ws + off);        off = align_up(off + N_EDGES * 4, 256);
    int* part = (int*)(ws + off);           off = align_up(off + NCHK * 4, 256);
    int* deg = (int*)(ws + off);            off = align_up(off + N_NODES * 4, 256);
    int* gstart = (int*)(ws + off);         off = align_up(off + (N_GRAPHS + 1) * 4, 256);
    short* W1t  = (short*)(ws + off);       off = align_up(off + (size_t)HID * IN_DIM * 2, 256);
    short* W2t  = (short*)(ws + off);       off = align_up(off + (size_t)HID * HID * 2, 256);
    short* lw1t = (short*)(ws + off);       off = align_up(off + (size_t)512 * XIN_PAD * 2, 256);
    short* lw2t = (short*)(ws + off);       off = align_up(off + (size_t)128 * HID * 2, 256);
    float* b1f  = (float*)(ws + off);       off = align_up(off + 512 * 4, 256);
    float* b2f  = (float*)(ws + off);       off = align_up(off + 512 * 4, 256);
    float* lb1f = (float*)(ws + off);       off = align_up(off + 512 * 4, 256);
    float* lb2f = (float*)(ws + off);       off = align_up(off + 128 * 4, 256);

    // ---- Detect float-tensor dtype (flag: 0=fp32, 1=bf16) ----
    detect_dtype_kernel<<<1, 256, 0, stream>>>(
        (const unsigned*)features, (unsigned)(N_NODES * IN_DIM / 2), dflag);

    // ---- Weight prep (one fused launch per mode) ----
    {
        int nblk = (788096 + 255) / 256;
        prep_weights_kernel<float, 0><<<nblk, 256, 0, stream>>>(
            (const float*)W1, (const float*)W2, (const float*)lw1, (const float*)lw2,
            (const float*)b1, (const float*)b2, (const float*)lb1, (const float*)lb2,
            W1t, W2t, lw1t, lw2t, b1f, b2f, lb1f, lb2f, dflag);
        prep_weights_kernel<bf16, 1><<<nblk, 256, 0, stream>>>(
            (const bf16*)W1, (const bf16*)W2, (const bf16*)lw1, (const bf16*)lw2,
            (const bf16*)b1, (const bf16*)b2, (const bf16*)lb1, (const bf16*)lb2,
            W1t, W2t, lw1t, lw2t, b1f, b2f, lb1f, lb2f, dflag);
    }

    // ---- CSR build (counting sort by dst) + graph ranges ----
    hipMemsetAsync(deg, 0, N_NODES * 4, stream);
    deg_kernel<<<(N_EDGES + 255) / 256, 256, 0, stream>>>(dst, deg);
    scan_partial_kernel<<<NCHK, 256, 0, stream>>>(deg, part);
    scan_parts_kernel<<<1, 1, 0, stream>>>(part, edge_start);
    scan_final_kernel<<<NCHK, 256, 0, stream>>>(deg, part, edge_start, cursor);
    fill_kernel<<<(N_EDGES + 255) / 256, 256, 0, stream>>>(src, dst, cursor, csr_src);
    gstart_kernel<<<(N_NODES + 256) / 256, 256, 0, stream>>>(node2graph, gstart);

    // ---- Layer 1: gather -> agg1 (bf16), MFMA GEMM -> h1 (bf16) ----
    gather_feat_kernel<float, 0><<<N_NODES / 4, 256, 0, stream>>>(
        (const float*)features, edge_start, csr_src, agg1, dflag);
    gather_feat_kernel<bf16, 1><<<N_NODES / 4, 256, 0, stream>>>(
        (const bf16*)features, edge_start, csr_src, agg1, dflag);
    {
        int nrt = (N_NODES + 127) / 128;   // 782
        mfma_gemm_kernel<4><<<swgrid(nrt, 4), 256, 0, stream>>>(
            (const short*)agg1, W1t, b1f, h1, N_NODES, IN_DIM, nrt);
    }

    // ---- Layer 2: gather h1 -> aggc (bf16), MFMA GEMM -> h2, pool (no atomics)
    gather_h_kernel<<<N_NODES / 4, 256, 0, stream>>>(h1, edge_start, csr_src, aggc);
    {
        int nrt = (N_NODES + 127) / 128;
        mfma_gemm_kernel<4><<<swgrid(nrt, 4), 256, 0, stream>>>(
            (const short*)aggc, W2t, b2f, h2, N_NODES, HID, nrt);
    }
    pool_graph_kernel<<<N_GRAPHS / 4, 256, 0, stream>>>(h2, gstart, hg);

    // ---- Head (all MFMA; padded-K chaining) ----
    {
        int nthr = (N_GRAPHS * XIN_PAD + 255) / 256;
        build_xin_kernel<float, 0><<<nthr, 256, 0, stream>>>(
            hg, gstart, (const float*)descriptors, xinb, dflag);
        build_xin_kernel<bf16, 1><<<nthr, 256, 0, stream>>>(
            hg, gstart, (const bf16*)descriptors, xinb, dflag);
    }
    {   // x1b[4000,512] = relu(xinb[4000,768] @ lw1t^T + lb1f)
        int nrt = (N_GRAPHS + 127) / 128;  // 32
        mfma_gemm_kernel<4><<<swgrid(nrt, 4), 256, 0, stream>>>(
            (const short*)xinb, lw1t, lb1f, x1b, N_GRAPHS, XIN_PAD, nrt);
    }
    {   // x2b cols 0..127 (stride 512) = relu(x1b @ lw2t^T + lb2f)
        int nrt = (N_GRAPHS + 127) / 128;
        mfma_gemm_kernel<1><<<swgrid(nrt, 1), 256, 0, stream>>>(
            (const short*)x1b, lw2t, lb2f, x2b, N_GRAPHS, HID, nrt);
    }
    {
        int nthr = (N_GRAPHS * N_CLASSES + 255) / 256;
        final_layer_kernel<float, 0><<<nthr, 256, 0, stream>>>(
            x2b, (const float*)cw, (const float*)cb, (float*)d_out, dflag);
        final_layer_kernel<bf16, 1><<<nthr, 256, 0, stream>>>(
            x2b, (const bf16*)cw, (const bf16*)cb, (bf16*)d_out, dflag);
    }
}